// Round 14
// baseline (451.187 us; speedup 1.0000x reference)
//
#include <hip/hip_runtime.h>
#include <hip/hip_bf16.h>

// ---------------------------------------------------------------------------
// Transformer block fwd (B=4,T=2048,C=1024,H=16,HS=64,FF=4096), fp32 in/out,
// bf16 MFMA internally.  Column-softmax (axis=-2) via two-pass maxless exp2.
// R14: attn_pv -> 1024 single-tile blocks (3 blocks/CU at 48KB LDS, big
//      tiles launched first per XCD chunk); BN=128 GEMMs back to 2-stage
//      (3-stage prologue/tail cost ~6us on nKT=16 with no per-dispatch gain).
// GEMMs are L2/L3-staging-bandwidth bound (~48KB/iter/CU at ~8.6TB/s) --
// pipeline depth / wave partition proven irrelevant (R10-R13).
// ---------------------------------------------------------------------------

#define T_SEQ 2048
#define SCALE2 0.1803368801f  // 0.125 * log2(e): 2^(s*SCALE2) == e^(s/8)

typedef __attribute__((ext_vector_type(8))) short short8;  // 8 x bf16 (4 VGPR)
typedef __attribute__((ext_vector_type(4))) float f32x4;   // MFMA 16x16 acc

typedef __attribute__((address_space(1))) unsigned int g_u32;
typedef __attribute__((address_space(3))) unsigned int l_u32;

__device__ __forceinline__ unsigned short f2bf(float f) {
  __hip_bfloat16 h = __float2bfloat16(f);
  union { __hip_bfloat16 h; unsigned short u; } x; x.h = h;
  return x.u;
}
__device__ __forceinline__ float bf2f(unsigned short u) {
  union { unsigned u; float f; } x; x.u = (unsigned)u << 16;
  return x.f;
}

__device__ __forceinline__ void g2lds16(const void* g, void* l) {
  // async global->LDS, 16B/lane; LDS dest is wave-uniform base + lane*16
  __builtin_amdgcn_global_load_lds((g_u32*)g, (l_u32*)l, 16, 0, 0);
}

// bijective XCD swizzle for nwg % 8 == 0: XCD x gets a contiguous work chunk
__device__ __forceinline__ int xcd_swz(int flat, int nwg) {
  if ((nwg & 7) != 0) return flat;
  return (flat & 7) * (nwg >> 3) + (flat >> 3);
}

// ---------------------------------------------------------------------------
// gemm256: C[M,N] = A[M,K] @ Bt[N,K]^T, 256xBN tile, BK=64, 8 waves,
// NSTG-buffered dynamic LDS with counted-vmcnt rotation (raw s_barrier).
// BN=128: 4Mx2N waves (per-wave 64x64), NSTG=2 (96KB LDS).
// BN=256: 2Mx4N waves (per-wave 128x64), NSTG=2 (128KB, FFN1 reuse tile).
// EPI 0: bf16 = acc; EPI 1: f32 = acc+bias+resid; EPI 2: bf16 = relu(acc+bias)
// Requires nKT = K/64 >= NSTG (true for all uses: 16 or 64).
// ---------------------------------------------------------------------------
template <int EPI, int BN, int NSTG>
__global__ __launch_bounds__(512, 2) void gemm256(
    const unsigned short* __restrict__ A, const unsigned short* __restrict__ Bt,
    int M, int N, int K,
    unsigned short* __restrict__ out16, float* __restrict__ outF,
    const float* __restrict__ bias, const float* __restrict__ resid) {
  constexpr int PM = (BN == 128) ? 4 : 2;  // waves along M
  constexpr int PN = 8 / PM;               // waves along N
  constexpr int WM = 256 / PM;             // per-wave M extent (64 or 128)
  constexpr int FM = WM / 16;              // M frags per wave (4 or 8)
  constexpr int WN = BN / PN;              // per-wave N extent (64)
  constexpr int FN = WN / 16;              // N frags per wave (4)
  constexpr int NB = (BN * 8) / 512;       // B-loads per wave per stage
  constexpr int NL = 4 + NB;               // loads per wave per stage
  extern __shared__ unsigned short lds[];
  unsigned short* ldsA = lds;                 // [NSTG][256*64]
  unsigned short* ldsB = lds + NSTG * 16384;  // [NSTG][BN*64]
  const int tid = threadIdx.x, lane = tid & 63, wid = tid >> 6;
  const int wm = wid / PN, wn = wid % PN;
  const int nx = gridDim.x;
  const int flat = blockIdx.y * nx + blockIdx.x;
  const int swz = xcd_swz(flat, nx * gridDim.y);
  const int mBase = (swz / nx) * 256, nBase = (swz % nx) * BN;

  f32x4 acc[FM][FN];
#pragma unroll
  for (int i = 0; i < FM; ++i)
#pragma unroll
    for (int j = 0; j < FN; ++j)
#pragma unroll
      for (int e = 0; e < 4; ++e) acc[i][j][e] = 0.f;

  auto stage = [&](int buf, int kt) {
    const int k0 = kt << 6;
#pragma unroll
    for (int it = 0; it < 4; ++it) {
      int g = it * 512 + tid;            // granule 0..2047 (16B = 8 bf16)
      int row = g >> 3, colL = g & 7;
      int col = colL ^ (row & 7);        // inverse-swizzled source (rule #21)
      g2lds16(A + ((size_t)(mBase + row) * K + k0 + col * 8),
              &ldsA[buf * 16384 + (it * 512 + wid * 64) * 8]);
    }
#pragma unroll
    for (int it = 0; it < NB; ++it) {
      int g = it * 512 + tid;
      int row = g >> 3, colL = g & 7;
      int col = colL ^ (row & 7);
      g2lds16(Bt + ((size_t)(nBase + row) * K + k0 + col * 8),
              &ldsB[buf * (BN * 64) + (it * 512 + wid * 64) * 8]);
    }
  };

  const int nKT = K >> 6;  // >= NSTG by construction
  // prologue: NSTG stages in flight; wait until stage 0 resident
#pragma unroll
  for (int i = 0; i < NSTG; ++i) stage(i, i);
  asm volatile("s_waitcnt vmcnt(%0)" ::"n"((NSTG - 1) * NL) : "memory");
  __builtin_amdgcn_sched_barrier(0);
  __builtin_amdgcn_s_barrier();
  __builtin_amdgcn_sched_barrier(0);

  for (int kt = 0; kt < nKT; ++kt) {
    const int cur = kt % NSTG;
    // ---- compute on buffer cur (tile kt resident for all waves) ----
    short8 bf[FN][2];  // B-frags once per K-tile (reused by all phases)
#pragma unroll
    for (int fn = 0; fn < FN; ++fn)
#pragma unroll
      for (int ks = 0; ks < 2; ++ks) {
        int r = wn * WN + fn * 16 + (lane & 15);
        int c = (ks * 4 + (lane >> 4)) ^ (r & 7);
        bf[fn][ks] = *(const short8*)&ldsB[cur * (BN * 64) + r * 64 + c * 8];
      }
#pragma unroll
    for (int mf = 0; mf < FM; ++mf) {  // FM phases of {2 ds_read, FN*2 MFMA}
      short8 af[2];
#pragma unroll
      for (int ks = 0; ks < 2; ++ks) {
        int r = wm * WM + mf * 16 + (lane & 15);
        int c = (ks * 4 + (lane >> 4)) ^ (r & 7);
        af[ks] = *(const short8*)&ldsA[cur * 16384 + r * 64 + c * 8];
      }
      __builtin_amdgcn_s_setprio(1);
#pragma unroll
      for (int fn = 0; fn < FN; ++fn)
#pragma unroll
        for (int ks = 0; ks < 2; ++ks)
          acc[mf][fn] = __builtin_amdgcn_mfma_f32_16x16x32_bf16(
              af[ks], bf[fn][ks], acc[mf][fn], 0, 0, 0);
      __builtin_amdgcn_s_setprio(0);
    }
    // ---- rotate: keep NSTG-1 stages in flight; wait until kt+1 resident ----
    if (kt + 1 < nKT) {
      asm volatile("s_waitcnt lgkmcnt(0)" ::: "memory");  // my reads of cur done
      __builtin_amdgcn_sched_barrier(0);
      __builtin_amdgcn_s_barrier();                        // everyone's done
      __builtin_amdgcn_sched_barrier(0);
      if (kt + NSTG < nKT) {
        stage(cur, kt + NSTG);  // overwrite cur (safe now)
        asm volatile("s_waitcnt vmcnt(%0)" ::"n"((NSTG - 1) * NL) : "memory");
      } else if (NSTG == 3 && kt + 2 < nKT) {
        asm volatile("s_waitcnt vmcnt(%0)" ::"n"(NL) : "memory");
      } else {
        asm volatile("s_waitcnt vmcnt(0)" ::: "memory");
      }
      __builtin_amdgcn_sched_barrier(0);
      __builtin_amdgcn_s_barrier();  // everyone's kt+1 landed
      __builtin_amdgcn_sched_barrier(0);
    }
  }

#pragma unroll
  for (int am = 0; am < FM; ++am)
#pragma unroll
    for (int fn = 0; fn < FN; ++fn) {
      int col = nBase + wn * WN + fn * 16 + (lane & 15);
      int row0 = mBase + wm * WM + am * 16 + ((lane >> 4) << 2);
      if (EPI == 0) {
#pragma unroll
        for (int r = 0; r < 4; ++r)
          out16[(size_t)(row0 + r) * N + col] = f2bf(acc[am][fn][r]);
      } else if (EPI == 1) {
        float bv = bias[col];
#pragma unroll
        for (int r = 0; r < 4; ++r) {
          size_t idx = (size_t)(row0 + r) * N + col;
          outF[idx] = acc[am][fn][r] + bv + resid[idx];
        }
      } else {
        float bv = bias[col];
#pragma unroll
        for (int r = 0; r < 4; ++r)
          out16[(size_t)(row0 + r) * N + col] =
              f2bf(fmaxf(acc[am][fn][r] + bv, 0.f));
      }
    }
}

// ---------------------------------------------------------------------------
// LayerNorm + bf16 cast.  One block per row of 1024.
// ---------------------------------------------------------------------------
__global__ __launch_bounds__(256) void ln_bf16(
    const float* __restrict__ x, const float* __restrict__ gw,
    const float* __restrict__ bw, unsigned short* __restrict__ out) {
  __shared__ float red[8];
  const int row = blockIdx.x, tid = threadIdx.x;
  const float4 v = ((const float4*)(x + (size_t)row * 1024))[tid];
  float s = v.x + v.y + v.z + v.w;
  float q = v.x * v.x + v.y * v.y + v.z * v.z + v.w * v.w;
#pragma unroll
  for (int off = 32; off >= 1; off >>= 1) {
    s += __shfl_down(s, off);
    q += __shfl_down(q, off);
  }
  const int lane = tid & 63, wid = tid >> 6;
  if (lane == 0) { red[wid] = s; red[4 + wid] = q; }
  __syncthreads();
  float S = red[0] + red[1] + red[2] + red[3];
  float Q = red[4] + red[5] + red[6] + red[7];
  float mu = S * (1.f / 1024.f);
  float var = Q * (1.f / 1024.f) - mu * mu;
  float rs = rsqrtf(var + 1e-5f);
  int c = tid * 4;
  ushort4 ov;
  ov.x = f2bf((v.x - mu) * rs * gw[c + 0] + bw[c + 0]);
  ov.y = f2bf((v.y - mu) * rs * gw[c + 1] + bw[c + 1]);
  ov.z = f2bf((v.z - mu) * rs * gw[c + 2] + bw[c + 2]);
  ov.w = f2bf((v.w - mu) * rs * gw[c + 3] + bw[c + 3]);
  *(ushort4*)&out[(size_t)row * 1024 + c] = ov;
}

// ---------------------------------------------------------------------------
// Weight packing: per-head Wq/Wk/Wv [H,C,HS] f32 -> Wqkv bf16 [3072][1024]
// ---------------------------------------------------------------------------
__global__ __launch_bounds__(256) void pack_qkv(
    const float* __restrict__ Wq, const float* __restrict__ Wk,
    const float* __restrict__ Wv, unsigned short* __restrict__ out) {
  __shared__ float tile[64 * 65];
  const int tid = threadIdx.x;
  const float* W = (blockIdx.z == 0) ? Wq : (blockIdx.z == 1) ? Wk : Wv;
  const int h = blockIdx.y, r0 = blockIdx.x * 64;
#pragma unroll
  for (int it = 0; it < 4; ++it) {
    int e4 = it * 256 + tid;
    int r = e4 >> 4, c4 = e4 & 15;
    float4 v = *(const float4*)&W[((size_t)h * 1024 + r0 + r) * 64 + c4 * 4];
    tile[r * 65 + c4 * 4 + 0] = v.x;
    tile[r * 65 + c4 * 4 + 1] = v.y;
    tile[r * 65 + c4 * 4 + 2] = v.z;
    tile[r * 65 + c4 * 4 + 3] = v.w;
  }
  __syncthreads();
#pragma unroll
  for (int it = 0; it < 4; ++it) {
    int e4 = it * 256 + tid;
    int d = e4 >> 4, r4 = e4 & 15;
    ushort4 ov;
    ov.x = f2bf(tile[(r4 * 4 + 0) * 65 + d]);
    ov.y = f2bf(tile[(r4 * 4 + 1) * 65 + d]);
    ov.z = f2bf(tile[(r4 * 4 + 2) * 65 + d]);
    ov.w = f2bf(tile[(r4 * 4 + 3) * 65 + d]);
    *(ushort4*)&out[(size_t)(blockIdx.z * 1024 + h * 64 + d) * 1024 + r0 +
                    r4 * 4] = ov;
  }
}

// Generic transpose+cast: in f32 [R,C] -> out bf16 [C,R].  grid (R/64, C/64).
__global__ __launch_bounds__(256) void transpose_cast(
    const float* __restrict__ in, unsigned short* __restrict__ out, int R,
    int C) {
  __shared__ float tile[64 * 65];
  const int tid = threadIdx.x;
  const int r0 = blockIdx.x * 64, c0 = blockIdx.y * 64;
#pragma unroll
  for (int it = 0; it < 4; ++it) {
    int e4 = it * 256 + tid;
    int r = e4 >> 4, c4 = e4 & 15;
    float4 v = *(const float4*)&in[(size_t)(r0 + r) * C + c0 + c4 * 4];
    tile[r * 65 + c4 * 4 + 0] = v.x;
    tile[r * 65 + c4 * 4 + 1] = v.y;
    tile[r * 65 + c4 * 4 + 2] = v.z;
    tile[r * 65 + c4 * 4 + 3] = v.w;
  }
  __syncthreads();
#pragma unroll
  for (int it = 0; it < 4; ++it) {
    int e4 = it * 256 + tid;
    int c = e4 >> 4, r4 = e4 & 15;
    ushort4 ov;
    ov.x = f2bf(tile[(r4 * 4 + 0) * 65 + c]);
    ov.y = f2bf(tile[(r4 * 4 + 1) * 65 + c]);
    ov.z = f2bf(tile[(r4 * 4 + 2) * 65 + c]);
    ov.w = f2bf(tile[(r4 * 4 + 3) * 65 + c]);
    *(ushort4*)&out[(size_t)(c0 + c) * R + r0 + r4 * 4] = ov;
  }
}

// V slice of qkv (cols 2048..3071) -> vT bf16 [B*H*64][T], PRE-SCALED by
// linv[t] = 1/(lp0[t]+lp1[t]).
__global__ __launch_bounds__(256) void vtrans(
    const unsigned short* __restrict__ qkv, const float* __restrict__ lpart,
    unsigned short* __restrict__ vT) {
  __shared__ unsigned short tile[64 * 66];
  const int tid = threadIdx.x;
  const int bh = blockIdx.y, b = bh >> 4, h = bh & 15;
  const int t0 = blockIdx.x * 64;
#pragma unroll
  for (int it = 0; it < 8; ++it) {
    int e2 = it * 256 + tid;
    int r = e2 >> 5, c2 = e2 & 31;
    unsigned v = *(const unsigned*)&qkv[(size_t)(b * T_SEQ + t0 + r) * 3072 +
                                        2048 + h * 64 + c2 * 2];
    float l0 = lpart[(size_t)bh * T_SEQ + t0 + r];
    float l1 = lpart[(size_t)(64 + bh) * T_SEQ + t0 + r];
    float li = 1.f / (l0 + l1);
    unsigned short lo = f2bf(bf2f((unsigned short)(v & 0xffff)) * li);
    unsigned short hi = f2bf(bf2f((unsigned short)(v >> 16)) * li);
    *(unsigned*)&tile[r * 66 + c2 * 2] = (unsigned)lo | ((unsigned)hi << 16);
  }
  __syncthreads();
#pragma unroll
  for (int it = 0; it < 8; ++it) {
    int e2 = it * 256 + tid;
    int d = e2 >> 5, t2 = e2 & 31;
    unsigned short a = tile[(t2 * 2) * 66 + d];
    unsigned short bb = tile[(t2 * 2 + 1) * 66 + d];
    unsigned pk = (unsigned)a | ((unsigned)bb << 16);
    *(unsigned*)&vT[(size_t)(bh * 64 + d) * T_SEQ + t0 + t2 * 2] = pk;
  }
}

// ---------------------------------------------------------------------------
// Attention pass A: partial l[s] = sum_{t in my half, t>=s} 2^(S*SCALE2).
// Barrier-free per-wave walk, 2048 blocks, 4 blocks/CU.
// ---------------------------------------------------------------------------
__global__ __launch_bounds__(256, 4) void attn_stats(
    const unsigned short* __restrict__ qkv, float* __restrict__ lpart) {
  __shared__ unsigned short qt[4][2][32 * 64];  // per-wave double buffer
  __shared__ float redL[4][2][64];
  const int tid = threadIdx.x, lane = tid & 63, w = tid >> 6;
  const int f = xcd_swz(blockIdx.y * 32 + blockIdx.x, 2048);
  const int half = f & 1, px = (f >> 1) & 15, bh = f >> 5;
  const int b = bh >> 4, h = bh & 15;
  const int sxA = px, sxB = 31 - px;
  const int sA = sxA * 64, sB = sxB * 64;
  const int m = half * 4 + w;  // t-tile stripe (mod 8)

  short8 kfA[4][2], kfB[4][2];
#pragma unroll
  for (int fn = 0; fn < 4; ++fn)
#pragma unroll
    for (int ks = 0; ks < 2; ++ks) {
      int d = 1024 + h * 64 + ks * 32 + ((lane >> 4) << 3);
      kfA[fn][ks] = *(const short8*)&qkv[(size_t)(b * T_SEQ + sA + fn * 16 +
                                                  (lane & 15)) * 3072 + d];
      kfB[fn][ks] = *(const short8*)&qkv[(size_t)(b * T_SEQ + sB + fn * 16 +
                                                  (lane & 15)) * 3072 + d];
    }
  float lA[4] = {0.f, 0.f, 0.f, 0.f}, lB[4] = {0.f, 0.f, 0.f, 0.f};

  auto stageQ = [&](int buf, int idx) {
    int t0 = idx * 32;
#pragma unroll
    for (int it = 0; it < 4; ++it) {
      int g = it * 64 + lane;
      int row = g >> 3;
      int col = (g & 7) ^ (row & 7);  // inverse-swizzled source
      g2lds16(qkv + ((size_t)(b * T_SEQ + t0 + row) * 3072 + h * 64 + col * 8),
              &qt[w][buf][it * 512]);
    }
  };

  auto accum = [&](const short8 (&af)[2], const short8 (&kf)[4][2],
                   float (&lacc)[4], int sBase, int tRow, bool diag) {
    f32x4 sc[4];
#pragma unroll
    for (int fn = 0; fn < 4; ++fn)
#pragma unroll
      for (int e = 0; e < 4; ++e) sc[fn][e] = 0.f;
    __builtin_amdgcn_s_setprio(1);
#pragma unroll
    for (int fn = 0; fn < 4; ++fn)
#pragma unroll
      for (int ks = 0; ks < 2; ++ks)
        sc[fn] = __builtin_amdgcn_mfma_f32_16x16x32_bf16(af[ks], kf[fn][ks],
                                                         sc[fn], 0, 0, 0);
    __builtin_amdgcn_s_setprio(0);
    if (diag) {
#pragma unroll
      for (int fn = 0; fn < 4; ++fn) {
        int s = sBase + fn * 16 + (lane & 15);
        float e0 = (tRow + 0 >= s) ? exp2f(sc[fn][0] * SCALE2) : 0.f;
        float e1 = (tRow + 1 >= s) ? exp2f(sc[fn][1] * SCALE2) : 0.f;
        float e2 = (tRow + 2 >= s) ? exp2f(sc[fn][2] * SCALE2) : 0.f;
        float e3 = (tRow + 3 >= s) ? exp2f(sc[fn][3] * SCALE2) : 0.f;
        lacc[fn] += (e0 + e1) + (e2 + e3);
      }
    } else {
#pragma unroll
      for (int fn = 0; fn < 4; ++fn) {
        float e0 = exp2f(sc[fn][0] * SCALE2);
        float e1 = exp2f(sc[fn][1] * SCALE2);
        float e2 = exp2f(sc[fn][2] * SCALE2);
        float e3 = exp2f(sc[fn][3] * SCALE2);
        lacc[fn] += (e0 + e1) + (e2 + e3);  // tree add: shorter dep chain
      }
    }
  };

  // first 32-row tile index >= 2*sxA in my stripe (idx == m mod 8)
  const int d0 = 2 * sxA - m;
  const int fi = m + (d0 > 0 ? (((d0 + 7) >> 3) << 3) : 0);
  int cur = 0;
  if (fi < 64) stageQ(0, fi);
  for (int idx = fi; idx < 64; idx += 8, cur ^= 1) {
    if (idx + 8 < 64) {
      stageQ(cur ^ 1, idx + 8);
      asm volatile("s_waitcnt vmcnt(4)" ::: "memory");  // cur buf resident
    } else {
      asm volatile("s_waitcnt vmcnt(0)" ::: "memory");
    }
    const int t0g = idx * 32;
    const bool doB = idx >= 2 * sxB;
#pragma unroll
    for (int mf = 0; mf < 2; ++mf) {
      short8 af[2];
#pragma unroll
      for (int ks = 0; ks < 2; ++ks) {
        int r = mf * 16 + (lane & 15);
        int c = (ks * 4 + (lane >> 4)) ^ (r & 7);
        af[ks] = *(const short8*)&qt[w][cur][r * 64 + c * 8];
      }
      int tRow = t0g + mf * 16 + ((lane >> 4) << 2);
      accum(af, kfA, lA, sA, tRow, idx <= 2 * sxA + 1);
      if (doB) accum(af, kfB, lB, sB, tRow, idx <= 2 * sxB + 1);
    }
  }
  // combine hi-groups (same col lives in lanes l, l+16, l+32, l+48)
#pragma unroll
  for (int fn = 0; fn < 4; ++fn) {
    lA[fn] += __shfl_down(lA[fn], 32);
    lA[fn] += __shfl_down(lA[fn], 16);
    lB[fn] += __shfl_down(lB[fn], 32);
    lB[fn] += __shfl_down(lB[fn], 16);
  }
  if (lane < 16) {
#pragma unroll
    for (int fn = 0; fn < 4; ++fn) {
      redL[w][0][fn * 16 + lane] = lA[fn];
      redL[w][1][fn * 16 + lane] = lB[fn];
    }
  }
  __syncthreads();
  if (tid < 128) {
    int which = tid >> 6;  // 0 -> A, 1 -> B
    float l = redL[0][which][lane] + redL[1][which][lane] +
              redL[2][which][lane] + redL[3][which][lane];
    int sbase = (which == 0) ? sA : sB;
    lpart[((size_t)half * 64 + bh) * T_SEQ + sbase + lane] = l;
  }
}

// ---------------------------------------------------------------------------
// Attention pass B (R14): ONE 128-row tile per block, 1024 blocks (16 x-tiles
// x 64 bh), 48KB LDS -> 3 blocks/CU.  Larger tiles (bx=15: 32 s-tiles)
// launch first within each XCD chunk; same-bh blocks XCD-local for K/V L2
// reuse.  QK^T as mfma(K,Q) -> packed b64 P-store; raw barriers + counted
// waits keep the K/V prefetch in flight across both compute phases.
// ---------------------------------------------------------------------------
__global__ __launch_bounds__(256, 2) void attn_pv(
    const unsigned short* __restrict__ qkv, const unsigned short* __restrict__ vT,
    unsigned short* __restrict__ o) {
  __shared__ unsigned short kbuf[2][64 * 64];
  __shared__ unsigned short vbuf[2][64 * 64];
  __shared__ unsigned short pl[128 * 64];
  const int tid = threadIdx.x, lane = tid & 63, wid = tid >> 6;
  const int f = xcd_swz(blockIdx.y * 16 + blockIdx.x, 1024);
  const int bx = 15 - (f & 15), bh = f >> 4;  // big tiles first per chunk
  const int b = bh >> 4, h = bh & 15;
  const int tA = bx * 128;
  const int nST = 2 * bx + 2;

  short8 qf[2][2];
#pragma unroll
  for (int mf = 0; mf < 2; ++mf)
#pragma unroll
    for (int ks = 0; ks < 2; ++ks) {
      int d = h * 64 + ks * 32 + ((lane >> 4) << 3);
      int rloc = wid * 32 + mf * 16 + (lane & 15);
      qf[mf][ks] =
          *(const short8*)&qkv[(size_t)(b * T_SEQ + tA + rloc) * 3072 + d];
    }
  f32x4 oacc[2][4];
#pragma unroll
  for (int i = 0; i < 2; ++i)
#pragma unroll
    for (int j = 0; j < 4; ++j)
#pragma unroll
      for (int e = 0; e < 4; ++e) oacc[i][j][e] = 0.f;

  auto stage = [&](int buf, int st) {
#pragma unroll
    for (int it = 0; it < 2; ++it) {
      int g = it * 256 + tid;            // granule 0..511 (16B each)
      int row = g >> 3, colL = g & 7;
      int col = colL ^ (row & 7);        // inverse-swizzled source
      g2lds16(qkv + ((size_t)(b * T_SEQ + st * 64 + row) * 3072 + 1024 +
                     h * 64 + col * 8),
              &kbuf[buf][(it * 256 + wid * 64) * 8]);
      g2lds16(vT + ((size_t)(bh * 64 + row) * T_SEQ + st * 64 + col * 8),
              &vbuf[buf][(it * 256 + wid * 64) * 8]);
    }
  };

  // QK^T as mfma(K, Q): lane holds 4 consecutive-s P values -> b64 store.
  auto qkstore = [&](int s0, bool maskNeeded, int cur) {
    f32x4 sc[4][2];
#pragma unroll
    for (int i = 0; i < 4; ++i)
#pragma unroll
      for (int j = 0; j < 2; ++j)
#pragma unroll
        for (int e = 0; e < 4; ++e) sc[i][j][e] = 0.f;
    __builtin_amdgcn_s_setprio(1);
#pragma unroll
    for (int fn = 0; fn < 4; ++fn)
#pragma unroll
      for (int ks = 0; ks < 2; ++ks) {
        int r = fn * 16 + (lane & 15);
        int c = (ks * 4 + (lane >> 4)) ^ (r & 7);
        short8 kfr = *(const short8*)&kbuf[cur][r * 64 + c * 8];
        sc[fn][0] = __builtin_amdgcn_mfma_f32_16x16x32_bf16(kfr, qf[0][ks],
                                                            sc[fn][0], 0, 0, 0);
        sc[fn][1] = __builtin_amdgcn_mfma_f32_16x16x32_bf16(kfr, qf[1][ks],
                                                            sc[fn][1], 0, 0, 0);
      }
    __builtin_amdgcn_s_setprio(0);
#pragma unroll
    for (int mf = 0; mf < 2; ++mf) {
      int tl = wid * 32 + mf * 16 + (lane & 15);  // pl row
      int tG = tA + tl;                            // global t
#pragma unroll
      for (int fn = 0; fn < 4; ++fn) {
        int sl = fn * 16 + ((lane >> 4) << 2);     // first of 4 consecutive s
        float p0 = exp2f(sc[fn][mf][0] * SCALE2);
        float p1 = exp2f(sc[fn][mf][1] * SCALE2);
        float p2 = exp2f(sc[fn][mf][2] * SCALE2);
        float p3 = exp2f(sc[fn][mf][3] * SCALE2);
        if (maskNeeded) {
          int sG = s0 + sl;
          p0 = (tG >= sG + 0) ? p0 : 0.f;
          p1 = (tG >= sG + 1) ? p1 : 0.f;
          p2 = (tG >= sG + 2) ? p2 : 0.f;
          p3 = (tG >= sG + 3) ? p3 : 0.f;
        }
        uint2 pk;
        pk.x = (unsigned)f2bf(p0) | ((unsigned)f2bf(p1) << 16);
        pk.y = (unsigned)f2bf(p2) | ((unsigned)f2bf(p3) << 16);
        int byteoff = tl * 128 + ((sl * 2) ^ ((tl & 7) << 4));
        *(uint2*)((char*)pl + byteoff) = pk;  // ds_write_b64
      }
    }
  };

  // PV: A = P (pl, swizzled), B^T = V-tile rows (vbuf, swizzled)
  auto pvphase = [&](int cur) {
    __builtin_amdgcn_s_setprio(1);
#pragma unroll
    for (int ks = 0; ks < 2; ++ks) {
      short8 pa[2];
#pragma unroll
      for (int mf = 0; mf < 2; ++mf) {
        int rowa = wid * 32 + mf * 16 + (lane & 15);
        int kb = ks * 64 + ((lane >> 4) << 4);
        pa[mf] = *(const short8*)((const char*)pl + rowa * 128 +
                                  (kb ^ ((rowa & 7) << 4)));
      }
#pragma unroll
      for (int df = 0; df < 4; ++df) {
        int r = df * 16 + (lane & 15);
        int c = (ks * 4 + (lane >> 4)) ^ (r & 7);
        short8 vb = *(const short8*)&vbuf[cur][r * 64 + c * 8];
        oacc[0][df] = __builtin_amdgcn_mfma_f32_16x16x32_bf16(pa[0], vb,
                                                              oacc[0][df], 0, 0, 0);
        oacc[1][df] = __builtin_amdgcn_mfma_f32_16x16x32_bf16(pa[1], vb,
                                                              oacc[1][df], 0, 0, 0);
      }
    }
    __builtin_amdgcn_s_setprio(0);
  };

  stage(0, 0);
  asm volatile("s_waitcnt vmcnt(0)" ::: "memory");
  __builtin_amdgcn_sched_barrier(0);
  __builtin_amdgcn_s_barrier();  // tile 0 resident
  __builtin_amdgcn_sched_barrier(0);

  int cur = 0;
  for (int st = 0; st < nST; ++st) {
    if (st + 1 < nST) stage(cur ^ 1, st + 1);  // in flight across both phases

    qkstore(st * 64, st >= nST - 2, cur);
    // pl visible (lgkm only -- prefetch stays in flight)
    asm volatile("s_waitcnt lgkmcnt(0)" ::: "memory");
    __builtin_amdgcn_sched_barrier(0);
    __builtin_amdgcn_s_barrier();
    __builtin_amdgcn_sched_barrier(0);
    pvphase(cur);
    // end of tile: drain prefetch + LDS ops, then release buffers
    asm volatile("s_waitcnt vmcnt(0) lgkmcnt(0)" ::: "memory");
    __builtin_amdgcn_sched_barrier(0);
    __builtin_amdgcn_s_barrier();
    __builtin_amdgcn_sched_barrier(0);
    cur ^= 1;
  }
  // write O as bf16 [B,T,C] (c = h*64+d)
#pragma unroll
  for (int mf = 0; mf < 2; ++mf)
#pragma unroll
    for (int df = 0; df < 4; ++df) {
      int d = h * 64 + df * 16 + (lane & 15);
      int ra = tA + wid * 32 + mf * 16 + ((lane >> 4) << 2);
#pragma unroll
      for (int r = 0; r < 4; ++r)
        o[(size_t)(b * T_SEQ + ra + r) * 1024 + d] = f2bf(oacc[mf][df][r]);
    }
}

// ---------------------------------------------------------------------------
extern "C" void kernel_launch(void* const* d_in, const int* in_sizes, int n_in,
                              void* d_out, int out_size, void* d_ws,
                              size_t ws_size, hipStream_t stream) {
  const float* x = (const float*)d_in[0];
  const float* Wq = (const float*)d_in[1];
  const float* Wk = (const float*)d_in[2];
  const float* Wv = (const float*)d_in[3];
  const float* Wo = (const float*)d_in[4];
  const float* bo = (const float*)d_in[5];
  const float* g1 = (const float*)d_in[6];
  const float* b1 = (const float*)d_in[7];
  const float* g2 = (const float*)d_in[8];
  const float* b2 = (const float*)d_in[9];
  const float* W1 = (const float*)d_in[10];
  const float* bf1 = (const float*)d_in[11];
  const float* W2 = (const float*)d_in[12];
  const float* bf2 = (const float*)d_in[13];
  float* out = (float*)d_out;

  char* ws = (char*)d_ws;
  size_t off = 0;
  auto alloc = [&](size_t bytes) {
    char* p = ws + off;
    off += (bytes + 255) & ~(size_t)255;
    return p;
  };
  unsigned short* Wqkv = (unsigned short*)alloc(3072ull * 1024 * 2);
  unsigned short* WoT = (unsigned short*)alloc(1024ull * 1024 * 2);
  unsigned short* W1T = (unsigned short*)alloc(4096ull * 1024 * 2);
  unsigned short* W2T = (unsigned short*)alloc(1024ull * 4096 * 2);
  unsigned short* hbuf = (unsigned short*)alloc(8192ull * 1024 * 2);  // h, then o
  char* regionE = alloc(8192ull * 3072 * 2 + 64ull * 64 * 2048 * 2);
  unsigned short* qkv = (unsigned short*)regionE;           // live: QKV..attn
  unsigned short* vT = (unsigned short*)(regionE + 8192ull * 3072 * 2);
  unsigned short* act = (unsigned short*)regionE;           // live: FFN
  float* lbuf = (float*)alloc(128ull * 2048 * 4);           // 2 halves of partials
  float* x1 = (float*)alloc(8192ull * 1024 * 4);
  unsigned short* fbuf = (unsigned short*)alloc(8192ull * 1024 * 2);
  unsigned short* obuf = hbuf;  // h dead after QKV GEMM

  (void)in_sizes; (void)n_in; (void)out_size; (void)ws_size;

  const size_t LDS128_2 = 2 * (16384 + 8192) * 2;   // 96 KB (BN=128, 2-stage)
  const size_t LDS256_2 = 2 * (16384 + 16384) * 2;  // 128 KB (BN=256, 2-stage)

  // weight packing (B^T bf16 layouts)
  pack_qkv<<<dim3(16, 16, 3), 256, 0, stream>>>(Wq, Wk, Wv, Wqkv);
  transpose_cast<<<dim3(16, 16), 256, 0, stream>>>(Wo, WoT, 1024, 1024);
  transpose_cast<<<dim3(16, 64), 256, 0, stream>>>(W1, W1T, 1024, 4096);
  transpose_cast<<<dim3(64, 16), 256, 0, stream>>>(W2, W2T, 4096, 1024);
  // LN1 -> h
  ln_bf16<<<8192, 256, 0, stream>>>(x, g1, b1, hbuf);
  // QKV projection: [8192,1024]@[1024,3072]  (768 blocks, 2-stage)
  gemm256<0, 128, 2><<<dim3(24, 32), 512, LDS128_2, stream>>>(
      hbuf, Wqkv, 8192, 3072, 1024, qkv, nullptr, nullptr, nullptr);
  // attention stats partials (2048 blocks, barrier-free waves)
  attn_stats<<<dim3(32, 64), 256, 0, stream>>>(qkv, lbuf);
  // V transpose, pre-scaled by combined linv
  vtrans<<<dim3(32, 64), 256, 0, stream>>>(qkv, lbuf, vT);
  // attention PV (1024 single-tile blocks, 3 blocks/CU)
  attn_pv<<<dim3(16, 64), 256, 0, stream>>>(qkv, vT, obuf);
  // x1 = x + O@Wo + bo   (256 blocks, 2-stage)
  gemm256<1, 128, 2><<<dim3(8, 32), 512, LDS128_2, stream>>>(
      obuf, WoT, 8192, 1024, 1024, nullptr, x1, bo, x);
  // LN2 -> f
  ln_bf16<<<8192, 256, 0, stream>>>(x1, g2, b2, fbuf);
  // FFN1: relu(f@W1 + bf1) -> act bf16 [8192,4096]  (512 blocks, BN=256)
  gemm256<2, 256, 2><<<dim3(16, 32), 512, LDS256_2, stream>>>(
      fbuf, W1T, 8192, 4096, 1024, act, nullptr, bf1, nullptr);
  // FFN2 + residual: out = x1 + act@W2 + bf2   (256 blocks, 2-stage)
  gemm256<1, 128, 2><<<dim3(8, 32), 512, LDS128_2, stream>>>(
      act, W2T, 8192, 1024, 4096, nullptr, out, bf2, x1);
}

// Round 15
// 427.087 us; speedup vs baseline: 1.0564x; 1.0564x over previous
//
#include <hip/hip_runtime.h>
#include <hip/hip_bf16.h>

// ---------------------------------------------------------------------------
// Transformer block fwd (B=4,T=2048,C=1024,H=16,HS=64,FF=4096), fp32 in/out,
// bf16 MFMA internally.  Column-softmax (axis=-2) via two-pass maxless exp2.
// R15: revert to the R9 configuration -- the best measured (426.4us).
// R10-R14 ledger: counted-vmcnt gemm loop (neutral), 3-stage (neutral/-),
// BN=128 FFN1 (-47us), 4Mx2N (neutral), single-tile attn_pv (-21us).
// GEMMs are L2/L3-staging-bandwidth bound; attn_pv row-pair amortizes
// K/V staging 2x -- both structures are at their measured local optima.
// ---------------------------------------------------------------------------

#define T_SEQ 2048
#define SCALE2 0.1803368801f  // 0.125 * log2(e): 2^(s*SCALE2) == e^(s/8)

typedef __attribute__((ext_vector_type(8))) short short8;  // 8 x bf16 (4 VGPR)
typedef __attribute__((ext_vector_type(4))) float f32x4;   // MFMA 16x16 acc

typedef __attribute__((address_space(1))) unsigned int g_u32;
typedef __attribute__((address_space(3))) unsigned int l_u32;

__device__ __forceinline__ unsigned short f2bf(float f) {
  __hip_bfloat16 h = __float2bfloat16(f);
  union { __hip_bfloat16 h; unsigned short u; } x; x.h = h;
  return x.u;
}
__device__ __forceinline__ float bf2f(unsigned short u) {
  union { unsigned u; float f; } x; x.u = (unsigned)u << 16;
  return x.f;
}

__device__ __forceinline__ void g2lds16(const void* g, void* l) {
  // async global->LDS, 16B/lane; LDS dest is wave-uniform base + lane*16
  __builtin_amdgcn_global_load_lds((g_u32*)g, (l_u32*)l, 16, 0, 0);
}

// bijective XCD swizzle for nwg % 8 == 0: XCD x gets a contiguous work chunk
__device__ __forceinline__ int xcd_swz(int flat, int nwg) {
  if ((nwg & 7) != 0) return flat;
  return (flat & 7) * (nwg >> 3) + (flat >> 3);
}

// ---------------------------------------------------------------------------
// gemm256: C[M,N] = A[M,K] @ Bt[N,K]^T, 256xBN tile, BK=64, 8 waves (2Mx4N),
// per-wave output 128x(BN/4).  Double-buffered dynamic LDS; stage-early /
// syncthreads-late loop (1 barrier per K-tile).
// EPI 0: bf16 = acc
// EPI 1: f32  = acc + bias[n] + resid[m,n]
// EPI 2: bf16 = relu(acc + bias[n])
// ---------------------------------------------------------------------------
template <int EPI, int BN>
__global__ __launch_bounds__(512, 2) void gemm256(
    const unsigned short* __restrict__ A, const unsigned short* __restrict__ Bt,
    int M, int N, int K,
    unsigned short* __restrict__ out16, float* __restrict__ outF,
    const float* __restrict__ bias, const float* __restrict__ resid) {
  constexpr int WN = BN / 4;   // per-wave N extent
  constexpr int FN = WN / 16;  // N frags per wave
  extern __shared__ unsigned short lds[];
  unsigned short* ldsA = lds;              // [2][256*64]
  unsigned short* ldsB = lds + 2 * 16384;  // [2][BN*64]
  const int tid = threadIdx.x, lane = tid & 63, wid = tid >> 6;
  const int wm = wid >> 2, wn = wid & 3;
  const int nx = gridDim.x;
  const int flat = blockIdx.y * nx + blockIdx.x;
  const int swz = xcd_swz(flat, nx * gridDim.y);
  const int mBase = (swz / nx) * 256, nBase = (swz % nx) * BN;

  f32x4 acc[8][FN];
#pragma unroll
  for (int i = 0; i < 8; ++i)
#pragma unroll
    for (int j = 0; j < FN; ++j)
#pragma unroll
      for (int e = 0; e < 4; ++e) acc[i][j][e] = 0.f;

  auto stage = [&](int buf, int kt) {
    const int k0 = kt << 6;
#pragma unroll
    for (int it = 0; it < 4; ++it) {
      int g = it * 512 + tid;            // granule 0..2047 (16B = 8 bf16)
      int row = g >> 3, colL = g & 7;
      int col = colL ^ (row & 7);        // inverse-swizzled source (rule #21)
      g2lds16(A + ((size_t)(mBase + row) * K + k0 + col * 8),
              &ldsA[buf * 16384 + (it * 512 + wid * 64) * 8]);
    }
#pragma unroll
    for (int it = 0; it < (BN * 8) / 512; ++it) {
      int g = it * 512 + tid;
      int row = g >> 3, colL = g & 7;
      int col = colL ^ (row & 7);
      g2lds16(Bt + ((size_t)(nBase + row) * K + k0 + col * 8),
              &ldsB[buf * (BN * 64) + (it * 512 + wid * 64) * 8]);
    }
  };

  const int nKT = K >> 6;
  stage(0, 0);
  __syncthreads();  // prologue drain
  int cur = 0;
  for (int kt = 0; kt < nKT; ++kt) {
    if (kt + 1 < nKT) stage(cur ^ 1, kt + 1);  // issue early...

    short8 bf[FN][2];  // B-frags once per K-tile (reused by all 4 phases)
#pragma unroll
    for (int fn = 0; fn < FN; ++fn)
#pragma unroll
      for (int ks = 0; ks < 2; ++ks) {
        int r = wn * WN + fn * 16 + (lane & 15);
        int c = (ks * 4 + (lane >> 4)) ^ (r & 7);
        bf[fn][ks] = *(const short8*)&ldsB[cur * (BN * 64) + r * 64 + c * 8];
      }
#pragma unroll
    for (int q = 0; q < 4; ++q) {  // 4 quadrant phases
      short8 af[2][2];
#pragma unroll
      for (int mf = 0; mf < 2; ++mf)
#pragma unroll
        for (int ks = 0; ks < 2; ++ks) {
          int r = wm * 128 + q * 32 + mf * 16 + (lane & 15);
          int c = (ks * 4 + (lane >> 4)) ^ (r & 7);
          af[mf][ks] = *(const short8*)&ldsA[cur * 16384 + r * 64 + c * 8];
        }
      __builtin_amdgcn_s_setprio(1);
#pragma unroll
      for (int mf = 0; mf < 2; ++mf)
#pragma unroll
        for (int fn = 0; fn < FN; ++fn)
#pragma unroll
          for (int ks = 0; ks < 2; ++ks)
            acc[q * 2 + mf][fn] = __builtin_amdgcn_mfma_f32_16x16x32_bf16(
                af[mf][ks], bf[fn][ks], acc[q * 2 + mf][fn], 0, 0, 0);
      __builtin_amdgcn_s_setprio(0);
    }
    __syncthreads();  // ...wait late: drains loads issued ~64 MFMA ago
    cur ^= 1;
  }

#pragma unroll
  for (int am = 0; am < 8; ++am)
#pragma unroll
    for (int fn = 0; fn < FN; ++fn) {
      int col = nBase + wn * WN + fn * 16 + (lane & 15);
      int row0 = mBase + wm * 128 + am * 16 + ((lane >> 4) << 2);
      if (EPI == 0) {
#pragma unroll
        for (int r = 0; r < 4; ++r)
          out16[(size_t)(row0 + r) * N + col] = f2bf(acc[am][fn][r]);
      } else if (EPI == 1) {
        float bv = bias[col];
#pragma unroll
        for (int r = 0; r < 4; ++r) {
          size_t idx = (size_t)(row0 + r) * N + col;
          outF[idx] = acc[am][fn][r] + bv + resid[idx];
        }
      } else {
        float bv = bias[col];
#pragma unroll
        for (int r = 0; r < 4; ++r)
          out16[(size_t)(row0 + r) * N + col] =
              f2bf(fmaxf(acc[am][fn][r] + bv, 0.f));
      }
    }
}

// ---------------------------------------------------------------------------
// LayerNorm + bf16 cast.  One block per row of 1024.
// ---------------------------------------------------------------------------
__global__ __launch_bounds__(256) void ln_bf16(
    const float* __restrict__ x, const float* __restrict__ gw,
    const float* __restrict__ bw, unsigned short* __restrict__ out) {
  __shared__ float red[8];
  const int row = blockIdx.x, tid = threadIdx.x;
  const float4 v = ((const float4*)(x + (size_t)row * 1024))[tid];
  float s = v.x + v.y + v.z + v.w;
  float q = v.x * v.x + v.y * v.y + v.z * v.z + v.w * v.w;
#pragma unroll
  for (int off = 32; off >= 1; off >>= 1) {
    s += __shfl_down(s, off);
    q += __shfl_down(q, off);
  }
  const int lane = tid & 63, wid = tid >> 6;
  if (lane == 0) { red[wid] = s; red[4 + wid] = q; }
  __syncthreads();
  float S = red[0] + red[1] + red[2] + red[3];
  float Q = red[4] + red[5] + red[6] + red[7];
  float mu = S * (1.f / 1024.f);
  float var = Q * (1.f / 1024.f) - mu * mu;
  float rs = rsqrtf(var + 1e-5f);
  int c = tid * 4;
  ushort4 ov;
  ov.x = f2bf((v.x - mu) * rs * gw[c + 0] + bw[c + 0]);
  ov.y = f2bf((v.y - mu) * rs * gw[c + 1] + bw[c + 1]);
  ov.z = f2bf((v.z - mu) * rs * gw[c + 2] + bw[c + 2]);
  ov.w = f2bf((v.w - mu) * rs * gw[c + 3] + bw[c + 3]);
  *(ushort4*)&out[(size_t)row * 1024 + c] = ov;
}

// ---------------------------------------------------------------------------
// Weight packing: per-head Wq/Wk/Wv [H,C,HS] f32 -> Wqkv bf16 [3072][1024]
// ---------------------------------------------------------------------------
__global__ __launch_bounds__(256) void pack_qkv(
    const float* __restrict__ Wq, const float* __restrict__ Wk,
    const float* __restrict__ Wv, unsigned short* __restrict__ out) {
  __shared__ float tile[64 * 65];
  const int tid = threadIdx.x;
  const float* W = (blockIdx.z == 0) ? Wq : (blockIdx.z == 1) ? Wk : Wv;
  const int h = blockIdx.y, r0 = blockIdx.x * 64;
#pragma unroll
  for (int it = 0; it < 4; ++it) {
    int e4 = it * 256 + tid;
    int r = e4 >> 4, c4 = e4 & 15;
    float4 v = *(const float4*)&W[((size_t)h * 1024 + r0 + r) * 64 + c4 * 4];
    tile[r * 65 + c4 * 4 + 0] = v.x;
    tile[r * 65 + c4 * 4 + 1] = v.y;
    tile[r * 65 + c4 * 4 + 2] = v.z;
    tile[r * 65 + c4 * 4 + 3] = v.w;
  }
  __syncthreads();
#pragma unroll
  for (int it = 0; it < 4; ++it) {
    int e4 = it * 256 + tid;
    int d = e4 >> 4, r4 = e4 & 15;
    ushort4 ov;
    ov.x = f2bf(tile[(r4 * 4 + 0) * 65 + d]);
    ov.y = f2bf(tile[(r4 * 4 + 1) * 65 + d]);
    ov.z = f2bf(tile[(r4 * 4 + 2) * 65 + d]);
    ov.w = f2bf(tile[(r4 * 4 + 3) * 65 + d]);
    *(ushort4*)&out[(size_t)(blockIdx.z * 1024 + h * 64 + d) * 1024 + r0 +
                    r4 * 4] = ov;
  }
}

// Generic transpose+cast: in f32 [R,C] -> out bf16 [C,R].  grid (R/64, C/64).
__global__ __launch_bounds__(256) void transpose_cast(
    const float* __restrict__ in, unsigned short* __restrict__ out, int R,
    int C) {
  __shared__ float tile[64 * 65];
  const int tid = threadIdx.x;
  const int r0 = blockIdx.x * 64, c0 = blockIdx.y * 64;
#pragma unroll
  for (int it = 0; it < 4; ++it) {
    int e4 = it * 256 + tid;
    int r = e4 >> 4, c4 = e4 & 15;
    float4 v = *(const float4*)&in[(size_t)(r0 + r) * C + c0 + c4 * 4];
    tile[r * 65 + c4 * 4 + 0] = v.x;
    tile[r * 65 + c4 * 4 + 1] = v.y;
    tile[r * 65 + c4 * 4 + 2] = v.z;
    tile[r * 65 + c4 * 4 + 3] = v.w;
  }
  __syncthreads();
#pragma unroll
  for (int it = 0; it < 4; ++it) {
    int e4 = it * 256 + tid;
    int c = e4 >> 4, r4 = e4 & 15;
    ushort4 ov;
    ov.x = f2bf(tile[(r4 * 4 + 0) * 65 + c]);
    ov.y = f2bf(tile[(r4 * 4 + 1) * 65 + c]);
    ov.z = f2bf(tile[(r4 * 4 + 2) * 65 + c]);
    ov.w = f2bf(tile[(r4 * 4 + 3) * 65 + c]);
    *(ushort4*)&out[(size_t)(c0 + c) * R + r0 + r4 * 4] = ov;
  }
}

// V slice of qkv (cols 2048..3071) -> vT bf16 [B*H*64][T], PRE-SCALED by
// linv[t] = 1/(lp0[t]+lp1[t]).
__global__ __launch_bounds__(256) void vtrans(
    const unsigned short* __restrict__ qkv, const float* __restrict__ lpart,
    unsigned short* __restrict__ vT) {
  __shared__ unsigned short tile[64 * 66];
  const int tid = threadIdx.x;
  const int bh = blockIdx.y, b = bh >> 4, h = bh & 15;
  const int t0 = blockIdx.x * 64;
#pragma unroll
  for (int it = 0; it < 8; ++it) {
    int e2 = it * 256 + tid;
    int r = e2 >> 5, c2 = e2 & 31;
    unsigned v = *(const unsigned*)&qkv[(size_t)(b * T_SEQ + t0 + r) * 3072 +
                                        2048 + h * 64 + c2 * 2];
    float l0 = lpart[(size_t)bh * T_SEQ + t0 + r];
    float l1 = lpart[(size_t)(64 + bh) * T_SEQ + t0 + r];
    float li = 1.f / (l0 + l1);
    unsigned short lo = f2bf(bf2f((unsigned short)(v & 0xffff)) * li);
    unsigned short hi = f2bf(bf2f((unsigned short)(v >> 16)) * li);
    *(unsigned*)&tile[r * 66 + c2 * 2] = (unsigned)lo | ((unsigned)hi << 16);
  }
  __syncthreads();
#pragma unroll
  for (int it = 0; it < 8; ++it) {
    int e2 = it * 256 + tid;
    int d = e2 >> 5, t2 = e2 & 31;
    unsigned short a = tile[(t2 * 2) * 66 + d];
    unsigned short bb = tile[(t2 * 2 + 1) * 66 + d];
    unsigned pk = (unsigned)a | ((unsigned)bb << 16);
    *(unsigned*)&vT[(size_t)(bh * 64 + d) * T_SEQ + t0 + t2 * 2] = pk;
  }
}

// ---------------------------------------------------------------------------
// Attention pass A: partial l[s] = sum_{t in my half, t>=s} 2^(S*SCALE2).
// Barrier-free per-wave walk, 2048 blocks, 4 blocks/CU.
// ---------------------------------------------------------------------------
__global__ __launch_bounds__(256, 4) void attn_stats(
    const unsigned short* __restrict__ qkv, float* __restrict__ lpart) {
  __shared__ unsigned short qt[4][2][32 * 64];  // per-wave double buffer
  __shared__ float redL[4][2][64];
  const int tid = threadIdx.x, lane = tid & 63, w = tid >> 6;
  const int f = xcd_swz(blockIdx.y * 32 + blockIdx.x, 2048);
  const int half = f & 1, px = (f >> 1) & 15, bh = f >> 5;
  const int b = bh >> 4, h = bh & 15;
  const int sxA = px, sxB = 31 - px;
  const int sA = sxA * 64, sB = sxB * 64;
  const int m = half * 4 + w;  // t-tile stripe (mod 8)

  short8 kfA[4][2], kfB[4][2];
#pragma unroll
  for (int fn = 0; fn < 4; ++fn)
#pragma unroll
    for (int ks = 0; ks < 2; ++ks) {
      int d = 1024 + h * 64 + ks * 32 + ((lane >> 4) << 3);
      kfA[fn][ks] = *(const short8*)&qkv[(size_t)(b * T_SEQ + sA + fn * 16 +
                                                  (lane & 15)) * 3072 + d];
      kfB[fn][ks] = *(const short8*)&qkv[(size_t)(b * T_SEQ + sB + fn * 16 +
                                                  (lane & 15)) * 3072 + d];
    }
  float lA[4] = {0.f, 0.f, 0.f, 0.f}, lB[4] = {0.f, 0.f, 0.f, 0.f};

  auto stageQ = [&](int buf, int idx) {
    int t0 = idx * 32;
#pragma unroll
    for (int it = 0; it < 4; ++it) {
      int g = it * 64 + lane;
      int row = g >> 3;
      int col = (g & 7) ^ (row & 7);  // inverse-swizzled source
      g2lds16(qkv + ((size_t)(b * T_SEQ + t0 + row) * 3072 + h * 64 + col * 8),
              &qt[w][buf][it * 512]);
    }
  };

  auto accum = [&](const short8 (&af)[2], const short8 (&kf)[4][2],
                   float (&lacc)[4], int sBase, int tRow, bool diag) {
    f32x4 sc[4];
#pragma unroll
    for (int fn = 0; fn < 4; ++fn)
#pragma unroll
      for (int e = 0; e < 4; ++e) sc[fn][e] = 0.f;
    __builtin_amdgcn_s_setprio(1);
#pragma unroll
    for (int fn = 0; fn < 4; ++fn)
#pragma unroll
      for (int ks = 0; ks < 2; ++ks)
        sc[fn] = __builtin_amdgcn_mfma_f32_16x16x32_bf16(af[ks], kf[fn][ks],
                                                         sc[fn], 0, 0, 0);
    __builtin_amdgcn_s_setprio(0);
    if (diag) {
#pragma unroll
      for (int fn = 0; fn < 4; ++fn) {
        int s = sBase + fn * 16 + (lane & 15);
        float e0 = (tRow + 0 >= s) ? exp2f(sc[fn][0] * SCALE2) : 0.f;
        float e1 = (tRow + 1 >= s) ? exp2f(sc[fn][1] * SCALE2) : 0.f;
        float e2 = (tRow + 2 >= s) ? exp2f(sc[fn][2] * SCALE2) : 0.f;
        float e3 = (tRow + 3 >= s) ? exp2f(sc[fn][3] * SCALE2) : 0.f;
        lacc[fn] += (e0 + e1) + (e2 + e3);
      }
    } else {
#pragma unroll
      for (int fn = 0; fn < 4; ++fn) {
        float e0 = exp2f(sc[fn][0] * SCALE2);
        float e1 = exp2f(sc[fn][1] * SCALE2);
        float e2 = exp2f(sc[fn][2] * SCALE2);
        float e3 = exp2f(sc[fn][3] * SCALE2);
        lacc[fn] += (e0 + e1) + (e2 + e3);  // tree add: shorter dep chain
      }
    }
  };

  // first 32-row tile index >= 2*sxA in my stripe (idx == m mod 8)
  const int d0 = 2 * sxA - m;
  const int fi = m + (d0 > 0 ? (((d0 + 7) >> 3) << 3) : 0);
  int cur = 0;
  if (fi < 64) stageQ(0, fi);
  for (int idx = fi; idx < 64; idx += 8, cur ^= 1) {
    if (idx + 8 < 64) {
      stageQ(cur ^ 1, idx + 8);
      asm volatile("s_waitcnt vmcnt(4)" ::: "memory");  // cur buf resident
    } else {
      asm volatile("s_waitcnt vmcnt(0)" ::: "memory");
    }
    const int t0g = idx * 32;
    const bool doB = idx >= 2 * sxB;
#pragma unroll
    for (int mf = 0; mf < 2; ++mf) {
      short8 af[2];
#pragma unroll
      for (int ks = 0; ks < 2; ++ks) {
        int r = mf * 16 + (lane & 15);
        int c = (ks * 4 + (lane >> 4)) ^ (r & 7);
        af[ks] = *(const short8*)&qt[w][cur][r * 64 + c * 8];
      }
      int tRow = t0g + mf * 16 + ((lane >> 4) << 2);
      accum(af, kfA, lA, sA, tRow, idx <= 2 * sxA + 1);
      if (doB) accum(af, kfB, lB, sB, tRow, idx <= 2 * sxB + 1);
    }
  }
  // combine hi-groups (same col lives in lanes l, l+16, l+32, l+48)
#pragma unroll
  for (int fn = 0; fn < 4; ++fn) {
    lA[fn] += __shfl_down(lA[fn], 32);
    lA[fn] += __shfl_down(lA[fn], 16);
    lB[fn] += __shfl_down(lB[fn], 32);
    lB[fn] += __shfl_down(lB[fn], 16);
  }
  if (lane < 16) {
#pragma unroll
    for (int fn = 0; fn < 4; ++fn) {
      redL[w][0][fn * 16 + lane] = lA[fn];
      redL[w][1][fn * 16 + lane] = lB[fn];
    }
  }
  __syncthreads();
  if (tid < 128) {
    int which = tid >> 6;  // 0 -> A, 1 -> B
    float l = redL[0][which][lane] + redL[1][which][lane] +
              redL[2][which][lane] + redL[3][which][lane];
    int sbase = (which == 0) ? sA : sB;
    lpart[((size_t)half * 64 + bh) * T_SEQ + sbase + lane] = l;
  }
}

// ---------------------------------------------------------------------------
// Attention pass B: row-tile pair per block, shared pl[128][64] (16KB),
// raw s_barrier + counted waits.  QK^T as mfma(K,Q): lane holds 4
// consecutive-s P values -> packed b64 P-store.
// ---------------------------------------------------------------------------
__global__ __launch_bounds__(256, 2) void attn_pv(
    const unsigned short* __restrict__ qkv, const unsigned short* __restrict__ vT,
    unsigned short* __restrict__ o) {
  __shared__ unsigned short kbuf[2][64 * 64];
  __shared__ unsigned short vbuf[2][64 * 64];
  __shared__ unsigned short pl[128 * 64];  // shared by A and B phases
  const int tid = threadIdx.x, lane = tid & 63, wid = tid >> 6;
  const int f = xcd_swz(blockIdx.y * 8 + blockIdx.x, 512);
  const int bx = f & 7, bh = f >> 3;
  const int b = bh >> 4, h = bh & 15;
  const int tA = bx * 128, tB = (15 - bx) * 128;
  const int nSTA = 2 * bx + 2, nSTB = 32 - 2 * bx;  // nSTA < nSTB always

  short8 qfA[2][2], qfB[2][2];
#pragma unroll
  for (int mf = 0; mf < 2; ++mf)
#pragma unroll
    for (int ks = 0; ks < 2; ++ks) {
      int d = h * 64 + ks * 32 + ((lane >> 4) << 3);
      int rloc = wid * 32 + mf * 16 + (lane & 15);
      qfA[mf][ks] =
          *(const short8*)&qkv[(size_t)(b * T_SEQ + tA + rloc) * 3072 + d];
      qfB[mf][ks] =
          *(const short8*)&qkv[(size_t)(b * T_SEQ + tB + rloc) * 3072 + d];
    }
  f32x4 oaccA[2][4], oaccB[2][4];
#pragma unroll
  for (int i = 0; i < 2; ++i)
#pragma unroll
    for (int j = 0; j < 4; ++j)
#pragma unroll
      for (int e = 0; e < 4; ++e) { oaccA[i][j][e] = 0.f; oaccB[i][j][e] = 0.f; }

  auto stage = [&](int buf, int st) {
#pragma unroll
    for (int it = 0; it < 2; ++it) {
      int g = it * 256 + tid;            // granule 0..511 (16B each)
      int row = g >> 3, colL = g & 7;
      int col = colL ^ (row & 7);        // inverse-swizzled source
      g2lds16(qkv + ((size_t)(b * T_SEQ + st * 64 + row) * 3072 + 1024 +
                     h * 64 + col * 8),
              &kbuf[buf][(it * 256 + wid * 64) * 8]);
      g2lds16(vT + ((size_t)(bh * 64 + row) * T_SEQ + st * 64 + col * 8),
              &vbuf[buf][(it * 256 + wid * 64) * 8]);
    }
  };

  // QK^T as mfma(K, Q): sc[fn][mf] has row = s-local, col = t-local.
  // Each lane holds P[t = wid*32+mf*16+(lane&15)][s = fn*16+(lane>>4)*4 + r]
  // -> 4 consecutive s = 8 contiguous bytes in row-major pl -> b64 store.
  auto qkstore = [&](const short8 (&qf)[2][2], int tBase, int s0,
                     bool maskNeeded, int cur) {
    f32x4 sc[4][2];
#pragma unroll
    for (int i = 0; i < 4; ++i)
#pragma unroll
      for (int j = 0; j < 2; ++j)
#pragma unroll
        for (int e = 0; e < 4; ++e) sc[i][j][e] = 0.f;
    __builtin_amdgcn_s_setprio(1);
#pragma unroll
    for (int fn = 0; fn < 4; ++fn)
#pragma unroll
      for (int ks = 0; ks < 2; ++ks) {
        int r = fn * 16 + (lane & 15);
        int c = (ks * 4 + (lane >> 4)) ^ (r & 7);
        short8 kfr = *(const short8*)&kbuf[cur][r * 64 + c * 8];
        sc[fn][0] = __builtin_amdgcn_mfma_f32_16x16x32_bf16(kfr, qf[0][ks],
                                                            sc[fn][0], 0, 0, 0);
        sc[fn][1] = __builtin_amdgcn_mfma_f32_16x16x32_bf16(kfr, qf[1][ks],
                                                            sc[fn][1], 0, 0, 0);
      }
    __builtin_amdgcn_s_setprio(0);
#pragma unroll
    for (int mf = 0; mf < 2; ++mf) {
      int tl = wid * 32 + mf * 16 + (lane & 15);  // pl row
      int tG = tBase + tl;                         // global t
#pragma unroll
      for (int fn = 0; fn < 4; ++fn) {
        int sl = fn * 16 + ((lane >> 4) << 2);     // first of 4 consecutive s
        float p0 = exp2f(sc[fn][mf][0] * SCALE2);
        float p1 = exp2f(sc[fn][mf][1] * SCALE2);
        float p2 = exp2f(sc[fn][mf][2] * SCALE2);
        float p3 = exp2f(sc[fn][mf][3] * SCALE2);
        if (maskNeeded) {
          int sG = s0 + sl;
          p0 = (tG >= sG + 0) ? p0 : 0.f;
          p1 = (tG >= sG + 1) ? p1 : 0.f;
          p2 = (tG >= sG + 2) ? p2 : 0.f;
          p3 = (tG >= sG + 3) ? p3 : 0.f;
        }
        uint2 pk;
        pk.x = (unsigned)f2bf(p0) | ((unsigned)f2bf(p1) << 16);
        pk.y = (unsigned)f2bf(p2) | ((unsigned)f2bf(p3) << 16);
        int byteoff = tl * 128 + ((sl * 2) ^ ((tl & 7) << 4));
        *(uint2*)((char*)pl + byteoff) = pk;  // ds_write_b64
      }
    }
  };

  // PV: A = P (pl, swizzled), B^T = V-tile rows (vbuf, swizzled)
  auto pvphase = [&](f32x4 (&oacc)[2][4], int cur) {
    __builtin_amdgcn_s_setprio(1);
#pragma unroll
    for (int ks = 0; ks < 2; ++ks) {
      short8 pa[2];
#pragma unroll
      for (int mf = 0; mf < 2; ++mf) {
        int rowa = wid * 32 + mf * 16 + (lane & 15);
        int kb = ks * 64 + ((lane >> 4) << 4);
        pa[mf] = *(const short8*)((const char*)pl + rowa * 128 +
                                  (kb ^ ((rowa & 7) << 4)));
      }
#pragma unroll
      for (int df = 0; df < 4; ++df) {
        int r = df * 16 + (lane & 15);
        int c = (ks * 4 + (lane >> 4)) ^ (r & 7);
        short8 vb = *(const short8*)&vbuf[cur][r * 64 + c * 8];
        oacc[0][df] = __builtin_amdgcn_mfma_f32_16x16x32_bf16(pa[0], vb,
                                                              oacc[0][df], 0, 0, 0);
        oacc[1][df] = __builtin_amdgcn_mfma_f32_16x16x32_bf16(pa[1], vb,
                                                              oacc[1][df], 0, 0, 0);
      }
    }
    __builtin_amdgcn_s_setprio(0);
  };

  // lgkm-only handoff barrier (does NOT drain the vmcnt prefetch)
  auto bar_lgkm = [&]() {
    asm volatile("s_waitcnt lgkmcnt(0)" ::: "memory");
    __builtin_amdgcn_sched_barrier(0);
    __builtin_amdgcn_s_barrier();
    __builtin_amdgcn_sched_barrier(0);
  };

  stage(0, 0);
  asm volatile("s_waitcnt vmcnt(0)" ::: "memory");
  __builtin_amdgcn_sched_barrier(0);
  __builtin_amdgcn_s_barrier();  // tile 0 resident
  __builtin_amdgcn_sched_barrier(0);

  int cur = 0;
  for (int st = 0; st < nSTB; ++st) {
    const int s0 = st * 64;
    const bool doA = st < nSTA;  // block-uniform

    if (st + 1 < nSTB) stage(cur ^ 1, st + 1);  // in flight across all phases

    if (doA) {
      qkstore(qfA, tA, s0, st >= nSTA - 2, cur);
      bar_lgkm();                 // pl(A) visible
      pvphase(oaccA, cur);
      bar_lgkm();                 // all reads of pl(A) retired
    }
    qkstore(qfB, tB, s0, st >= nSTB - 2, cur);
    bar_lgkm();                   // pl(B) visible
    pvphase(oaccB, cur);
    // end of tile: drain prefetch + all LDS ops, then release buffers
    asm volatile("s_waitcnt vmcnt(0) lgkmcnt(0)" ::: "memory");
    __builtin_amdgcn_sched_barrier(0);
    __builtin_amdgcn_s_barrier();
    __builtin_amdgcn_sched_barrier(0);
    cur ^= 1;
  }
  // write O as bf16 [B,T,C] (c = h*64+d)
#pragma unroll
  for (int mf = 0; mf < 2; ++mf)
#pragma unroll
    for (int df = 0; df < 4; ++df) {
      int d = h * 64 + df * 16 + (lane & 15);
      int ra = tA + wid * 32 + mf * 16 + ((lane >> 4) << 2);
      int rb = tB + wid * 32 + mf * 16 + ((lane >> 4) << 2);
#pragma unroll
      for (int r = 0; r < 4; ++r) {
        o[(size_t)(b * T_SEQ + ra + r) * 1024 + d] = f2bf(oaccA[mf][df][r]);
        o[(size_t)(b * T_SEQ + rb + r) * 1024 + d] = f2bf(oaccB[mf][df][r]);
      }
    }
}

// ---------------------------------------------------------------------------
extern "C" void kernel_launch(void* const* d_in, const int* in_sizes, int n_in,
                              void* d_out, int out_size, void* d_ws,
                              size_t ws_size, hipStream_t stream) {
  const float* x = (const float*)d_in[0];
  const float* Wq = (const float*)d_in[1];
  const float* Wk = (const float*)d_in[2];
  const float* Wv = (const float*)d_in[3];
  const float* Wo = (const float*)d_in[4];
  const float* bo = (const float*)d_in[5];
  const float* g1 = (const float*)d_in[6];
  const float* b1 = (const float*)d_in[7];
  const float* g2 = (const float*)d_in[8];
  const float* b2 = (const float*)d_in[9];
  const float* W1 = (const float*)d_in[10];
  const float* bf1 = (const float*)d_in[11];
  const float* W2 = (const float*)d_in[12];
  const float* bf2 = (const float*)d_in[13];
  float* out = (float*)d_out;

  char* ws = (char*)d_ws;
  size_t off = 0;
  auto alloc = [&](size_t bytes) {
    char* p = ws + off;
    off += (bytes + 255) & ~(size_t)255;
    return p;
  };
  unsigned short* Wqkv = (unsigned short*)alloc(3072ull * 1024 * 2);
  unsigned short* WoT = (unsigned short*)alloc(1024ull * 1024 * 2);
  unsigned short* W1T = (unsigned short*)alloc(4096ull * 1024 * 2);
  unsigned short* W2T = (unsigned short*)alloc(1024ull * 4096 * 2);
  unsigned short* hbuf = (unsigned short*)alloc(8192ull * 1024 * 2);  // h, then o
  char* regionE = alloc(8192ull * 3072 * 2 + 64ull * 64 * 2048 * 2);
  unsigned short* qkv = (unsigned short*)regionE;           // live: QKV..attn
  unsigned short* vT = (unsigned short*)(regionE + 8192ull * 3072 * 2);
  unsigned short* act = (unsigned short*)regionE;           // live: FFN
  float* lbuf = (float*)alloc(128ull * 2048 * 4);           // 2 halves of partials
  float* x1 = (float*)alloc(8192ull * 1024 * 4);
  unsigned short* fbuf = (unsigned short*)alloc(8192ull * 1024 * 2);
  unsigned short* obuf = hbuf;  // h dead after QKV GEMM

  (void)in_sizes; (void)n_in; (void)out_size; (void)ws_size;

  const size_t LDS128 = (2 * 16384 + 2 * 128 * 64) * 2;  // 96 KB
  const size_t LDS256 = (2 * 16384 + 2 * 256 * 64) * 2;  // 128 KB

  // weight packing (B^T bf16 layouts)
  pack_qkv<<<dim3(16, 16, 3), 256, 0, stream>>>(Wq, Wk, Wv, Wqkv);
  transpose_cast<<<dim3(16, 16), 256, 0, stream>>>(Wo, WoT, 1024, 1024);
  transpose_cast<<<dim3(16, 64), 256, 0, stream>>>(W1, W1T, 1024, 4096);
  transpose_cast<<<dim3(64, 16), 256, 0, stream>>>(W2, W2T, 4096, 1024);
  // LN1 -> h
  ln_bf16<<<8192, 256, 0, stream>>>(x, g1, b1, hbuf);
  // QKV projection: [8192,1024]@[1024,3072]  (768 blocks = 3 exact waves)
  gemm256<0, 128><<<dim3(24, 32), 512, LDS128, stream>>>(
      hbuf, Wqkv, 8192, 3072, 1024, qkv, nullptr, nullptr, nullptr);
  // attention stats partials (2048 blocks, barrier-free waves)
  attn_stats<<<dim3(32, 64), 256, 0, stream>>>(qkv, lbuf);
  // V transpose, pre-scaled by combined linv
  vtrans<<<dim3(32, 64), 256, 0, stream>>>(qkv, lbuf, vT);
  // attention PV
  attn_pv<<<dim3(8, 64), 256, 0, stream>>>(qkv, vT, obuf);
  // x1 = x + O@Wo + bo   (256 blocks = 1 exact wave)
  gemm256<1, 128><<<dim3(8, 32), 512, LDS128, stream>>>(
      obuf, WoT, 8192, 1024, 1024, nullptr, x1, bo, x);
  // LN2 -> f
  ln_bf16<<<8192, 256, 0, stream>>>(x1, g2, b2, fbuf);
  // FFN1: relu(f@W1 + bf1) -> act bf16 [8192,4096]  (512 blocks = 2 waves)
  gemm256<2, 256><<<dim3(16, 32), 512, LDS256, stream>>>(
      fbuf, W1T, 8192, 4096, 1024, act, nullptr, bf1, nullptr);
  // FFN2 + residual: out = x1 + act@W2 + bf2   (256 blocks = 1 exact wave)
  gemm256<1, 128><<<dim3(8, 32), 512, LDS128, stream>>>(
      act, W2T, 8192, 1024, 4096, nullptr, out, bf2, x1);
}

// Round 16
// 424.252 us; speedup vs baseline: 1.0635x; 1.0067x over previous
//
#include <hip/hip_runtime.h>
#include <hip/hip_bf16.h>

// ---------------------------------------------------------------------------
// Transformer block fwd (B=4,T=2048,C=1024,H=16,HS=64,FF=4096), fp32 in/out,
// bf16 MFMA internally.  Column-softmax (axis=-2) via two-pass maxless exp2.
// R16: attn_pv merged middle phase -- split plA/plB (64KB LDS) so qkB's
//      exp2/VALU work overlaps pvA's MFMA in one stream (separate pipes,
//      m114/T15); 3 barriers per A-tile instead of 4.  Rest = R15 (best).
// ---------------------------------------------------------------------------

#define T_SEQ 2048
#define SCALE2 0.1803368801f  // 0.125 * log2(e): 2^(s*SCALE2) == e^(s/8)

typedef __attribute__((ext_vector_type(8))) short short8;  // 8 x bf16 (4 VGPR)
typedef __attribute__((ext_vector_type(4))) float f32x4;   // MFMA 16x16 acc

typedef __attribute__((address_space(1))) unsigned int g_u32;
typedef __attribute__((address_space(3))) unsigned int l_u32;

__device__ __forceinline__ unsigned short f2bf(float f) {
  __hip_bfloat16 h = __float2bfloat16(f);
  union { __hip_bfloat16 h; unsigned short u; } x; x.h = h;
  return x.u;
}
__device__ __forceinline__ float bf2f(unsigned short u) {
  union { unsigned u; float f; } x; x.u = (unsigned)u << 16;
  return x.f;
}

__device__ __forceinline__ void g2lds16(const void* g, void* l) {
  // async global->LDS, 16B/lane; LDS dest is wave-uniform base + lane*16
  __builtin_amdgcn_global_load_lds((g_u32*)g, (l_u32*)l, 16, 0, 0);
}

// bijective XCD swizzle for nwg % 8 == 0: XCD x gets a contiguous work chunk
__device__ __forceinline__ int xcd_swz(int flat, int nwg) {
  if ((nwg & 7) != 0) return flat;
  return (flat & 7) * (nwg >> 3) + (flat >> 3);
}

// ---------------------------------------------------------------------------
// gemm256: C[M,N] = A[M,K] @ Bt[N,K]^T, 256xBN tile, BK=64, 8 waves (2Mx4N),
// per-wave output 128x(BN/4).  Double-buffered dynamic LDS; stage-early /
// syncthreads-late loop (1 barrier per K-tile).
// EPI 0: bf16 = acc
// EPI 1: f32  = acc + bias[n] + resid[m,n]
// EPI 2: bf16 = relu(acc + bias[n])
// ---------------------------------------------------------------------------
template <int EPI, int BN>
__global__ __launch_bounds__(512, 2) void gemm256(
    const unsigned short* __restrict__ A, const unsigned short* __restrict__ Bt,
    int M, int N, int K,
    unsigned short* __restrict__ out16, float* __restrict__ outF,
    const float* __restrict__ bias, const float* __restrict__ resid) {
  constexpr int WN = BN / 4;   // per-wave N extent
  constexpr int FN = WN / 16;  // N frags per wave
  extern __shared__ unsigned short lds[];
  unsigned short* ldsA = lds;              // [2][256*64]
  unsigned short* ldsB = lds + 2 * 16384;  // [2][BN*64]
  const int tid = threadIdx.x, lane = tid & 63, wid = tid >> 6;
  const int wm = wid >> 2, wn = wid & 3;
  const int nx = gridDim.x;
  const int flat = blockIdx.y * nx + blockIdx.x;
  const int swz = xcd_swz(flat, nx * gridDim.y);
  const int mBase = (swz / nx) * 256, nBase = (swz % nx) * BN;

  f32x4 acc[8][FN];
#pragma unroll
  for (int i = 0; i < 8; ++i)
#pragma unroll
    for (int j = 0; j < FN; ++j)
#pragma unroll
      for (int e = 0; e < 4; ++e) acc[i][j][e] = 0.f;

  auto stage = [&](int buf, int kt) {
    const int k0 = kt << 6;
#pragma unroll
    for (int it = 0; it < 4; ++it) {
      int g = it * 512 + tid;            // granule 0..2047 (16B = 8 bf16)
      int row = g >> 3, colL = g & 7;
      int col = colL ^ (row & 7);        // inverse-swizzled source (rule #21)
      g2lds16(A + ((size_t)(mBase + row) * K + k0 + col * 8),
              &ldsA[buf * 16384 + (it * 512 + wid * 64) * 8]);
    }
#pragma unroll
    for (int it = 0; it < (BN * 8) / 512; ++it) {
      int g = it * 512 + tid;
      int row = g >> 3, colL = g & 7;
      int col = colL ^ (row & 7);
      g2lds16(Bt + ((size_t)(nBase + row) * K + k0 + col * 8),
              &ldsB[buf * (BN * 64) + (it * 512 + wid * 64) * 8]);
    }
  };

  const int nKT = K >> 6;
  stage(0, 0);
  __syncthreads();  // prologue drain
  int cur = 0;
  for (int kt = 0; kt < nKT; ++kt) {
    if (kt + 1 < nKT) stage(cur ^ 1, kt + 1);  // issue early...

    short8 bf[FN][2];  // B-frags once per K-tile (reused by all 4 phases)
#pragma unroll
    for (int fn = 0; fn < FN; ++fn)
#pragma unroll
      for (int ks = 0; ks < 2; ++ks) {
        int r = wn * WN + fn * 16 + (lane & 15);
        int c = (ks * 4 + (lane >> 4)) ^ (r & 7);
        bf[fn][ks] = *(const short8*)&ldsB[cur * (BN * 64) + r * 64 + c * 8];
      }
#pragma unroll
    for (int q = 0; q < 4; ++q) {  // 4 quadrant phases
      short8 af[2][2];
#pragma unroll
      for (int mf = 0; mf < 2; ++mf)
#pragma unroll
        for (int ks = 0; ks < 2; ++ks) {
          int r = wm * 128 + q * 32 + mf * 16 + (lane & 15);
          int c = (ks * 4 + (lane >> 4)) ^ (r & 7);
          af[mf][ks] = *(const short8*)&ldsA[cur * 16384 + r * 64 + c * 8];
        }
      __builtin_amdgcn_s_setprio(1);
#pragma unroll
      for (int mf = 0; mf < 2; ++mf)
#pragma unroll
        for (int fn = 0; fn < FN; ++fn)
#pragma unroll
          for (int ks = 0; ks < 2; ++ks)
            acc[q * 2 + mf][fn] = __builtin_amdgcn_mfma_f32_16x16x32_bf16(
                af[mf][ks], bf[fn][ks], acc[q * 2 + mf][fn], 0, 0, 0);
      __builtin_amdgcn_s_setprio(0);
    }
    __syncthreads();  // ...wait late: drains loads issued ~64 MFMA ago
    cur ^= 1;
  }

#pragma unroll
  for (int am = 0; am < 8; ++am)
#pragma unroll
    for (int fn = 0; fn < FN; ++fn) {
      int col = nBase + wn * WN + fn * 16 + (lane & 15);
      int row0 = mBase + wm * 128 + am * 16 + ((lane >> 4) << 2);
      if (EPI == 0) {
#pragma unroll
        for (int r = 0; r < 4; ++r)
          out16[(size_t)(row0 + r) * N + col] = f2bf(acc[am][fn][r]);
      } else if (EPI == 1) {
        float bv = bias[col];
#pragma unroll
        for (int r = 0; r < 4; ++r) {
          size_t idx = (size_t)(row0 + r) * N + col;
          outF[idx] = acc[am][fn][r] + bv + resid[idx];
        }
      } else {
        float bv = bias[col];
#pragma unroll
        for (int r = 0; r < 4; ++r)
          out16[(size_t)(row0 + r) * N + col] =
              f2bf(fmaxf(acc[am][fn][r] + bv, 0.f));
      }
    }
}

// ---------------------------------------------------------------------------
// LayerNorm + bf16 cast.  One block per row of 1024.
// ---------------------------------------------------------------------------
__global__ __launch_bounds__(256) void ln_bf16(
    const float* __restrict__ x, const float* __restrict__ gw,
    const float* __restrict__ bw, unsigned short* __restrict__ out) {
  __shared__ float red[8];
  const int row = blockIdx.x, tid = threadIdx.x;
  const float4 v = ((const float4*)(x + (size_t)row * 1024))[tid];
  float s = v.x + v.y + v.z + v.w;
  float q = v.x * v.x + v.y * v.y + v.z * v.z + v.w * v.w;
#pragma unroll
  for (int off = 32; off >= 1; off >>= 1) {
    s += __shfl_down(s, off);
    q += __shfl_down(q, off);
  }
  const int lane = tid & 63, wid = tid >> 6;
  if (lane == 0) { red[wid] = s; red[4 + wid] = q; }
  __syncthreads();
  float S = red[0] + red[1] + red[2] + red[3];
  float Q = red[4] + red[5] + red[6] + red[7];
  float mu = S * (1.f / 1024.f);
  float var = Q * (1.f / 1024.f) - mu * mu;
  float rs = rsqrtf(var + 1e-5f);
  int c = tid * 4;
  ushort4 ov;
  ov.x = f2bf((v.x - mu) * rs * gw[c + 0] + bw[c + 0]);
  ov.y = f2bf((v.y - mu) * rs * gw[c + 1] + bw[c + 1]);
  ov.z = f2bf((v.z - mu) * rs * gw[c + 2] + bw[c + 2]);
  ov.w = f2bf((v.w - mu) * rs * gw[c + 3] + bw[c + 3]);
  *(ushort4*)&out[(size_t)row * 1024 + c] = ov;
}

// ---------------------------------------------------------------------------
// Weight packing: per-head Wq/Wk/Wv [H,C,HS] f32 -> Wqkv bf16 [3072][1024]
// ---------------------------------------------------------------------------
__global__ __launch_bounds__(256) void pack_qkv(
    const float* __restrict__ Wq, const float* __restrict__ Wk,
    const float* __restrict__ Wv, unsigned short* __restrict__ out) {
  __shared__ float tile[64 * 65];
  const int tid = threadIdx.x;
  const float* W = (blockIdx.z == 0) ? Wq : (blockIdx.z == 1) ? Wk : Wv;
  const int h = blockIdx.y, r0 = blockIdx.x * 64;
#pragma unroll
  for (int it = 0; it < 4; ++it) {
    int e4 = it * 256 + tid;
    int r = e4 >> 4, c4 = e4 & 15;
    float4 v = *(const float4*)&W[((size_t)h * 1024 + r0 + r) * 64 + c4 * 4];
    tile[r * 65 + c4 * 4 + 0] = v.x;
    tile[r * 65 + c4 * 4 + 1] = v.y;
    tile[r * 65 + c4 * 4 + 2] = v.z;
    tile[r * 65 + c4 * 4 + 3] = v.w;
  }
  __syncthreads();
#pragma unroll
  for (int it = 0; it < 4; ++it) {
    int e4 = it * 256 + tid;
    int d = e4 >> 4, r4 = e4 & 15;
    ushort4 ov;
    ov.x = f2bf(tile[(r4 * 4 + 0) * 65 + d]);
    ov.y = f2bf(tile[(r4 * 4 + 1) * 65 + d]);
    ov.z = f2bf(tile[(r4 * 4 + 2) * 65 + d]);
    ov.w = f2bf(tile[(r4 * 4 + 3) * 65 + d]);
    *(ushort4*)&out[(size_t)(blockIdx.z * 1024 + h * 64 + d) * 1024 + r0 +
                    r4 * 4] = ov;
  }
}

// Generic transpose+cast: in f32 [R,C] -> out bf16 [C,R].  grid (R/64, C/64).
__global__ __launch_bounds__(256) void transpose_cast(
    const float* __restrict__ in, unsigned short* __restrict__ out, int R,
    int C) {
  __shared__ float tile[64 * 65];
  const int tid = threadIdx.x;
  const int r0 = blockIdx.x * 64, c0 = blockIdx.y * 64;
#pragma unroll
  for (int it = 0; it < 4; ++it) {
    int e4 = it * 256 + tid;
    int r = e4 >> 4, c4 = e4 & 15;
    float4 v = *(const float4*)&in[(size_t)(r0 + r) * C + c0 + c4 * 4];
    tile[r * 65 + c4 * 4 + 0] = v.x;
    tile[r * 65 + c4 * 4 + 1] = v.y;
    tile[r * 65 + c4 * 4 + 2] = v.z;
    tile[r * 65 + c4 * 4 + 3] = v.w;
  }
  __syncthreads();
#pragma unroll
  for (int it = 0; it < 4; ++it) {
    int e4 = it * 256 + tid;
    int c = e4 >> 4, r4 = e4 & 15;
    ushort4 ov;
    ov.x = f2bf(tile[(r4 * 4 + 0) * 65 + c]);
    ov.y = f2bf(tile[(r4 * 4 + 1) * 65 + c]);
    ov.z = f2bf(tile[(r4 * 4 + 2) * 65 + c]);
    ov.w = f2bf(tile[(r4 * 4 + 3) * 65 + c]);
    *(ushort4*)&out[(size_t)(c0 + c) * R + r0 + r4 * 4] = ov;
  }
}

// V slice of qkv (cols 2048..3071) -> vT bf16 [B*H*64][T], PRE-SCALED by
// linv[t] = 1/(lp0[t]+lp1[t]).
__global__ __launch_bounds__(256) void vtrans(
    const unsigned short* __restrict__ qkv, const float* __restrict__ lpart,
    unsigned short* __restrict__ vT) {
  __shared__ unsigned short tile[64 * 66];
  const int tid = threadIdx.x;
  const int bh = blockIdx.y, b = bh >> 4, h = bh & 15;
  const int t0 = blockIdx.x * 64;
#pragma unroll
  for (int it = 0; it < 8; ++it) {
    int e2 = it * 256 + tid;
    int r = e2 >> 5, c2 = e2 & 31;
    unsigned v = *(const unsigned*)&qkv[(size_t)(b * T_SEQ + t0 + r) * 3072 +
                                        2048 + h * 64 + c2 * 2];
    float l0 = lpart[(size_t)bh * T_SEQ + t0 + r];
    float l1 = lpart[(size_t)(64 + bh) * T_SEQ + t0 + r];
    float li = 1.f / (l0 + l1);
    unsigned short lo = f2bf(bf2f((unsigned short)(v & 0xffff)) * li);
    unsigned short hi = f2bf(bf2f((unsigned short)(v >> 16)) * li);
    *(unsigned*)&tile[r * 66 + c2 * 2] = (unsigned)lo | ((unsigned)hi << 16);
  }
  __syncthreads();
#pragma unroll
  for (int it = 0; it < 8; ++it) {
    int e2 = it * 256 + tid;
    int d = e2 >> 5, t2 = e2 & 31;
    unsigned short a = tile[(t2 * 2) * 66 + d];
    unsigned short bb = tile[(t2 * 2 + 1) * 66 + d];
    unsigned pk = (unsigned)a | ((unsigned)bb << 16);
    *(unsigned*)&vT[(size_t)(bh * 64 + d) * T_SEQ + t0 + t2 * 2] = pk;
  }
}

// ---------------------------------------------------------------------------
// Attention pass A: partial l[s] = sum_{t in my half, t>=s} 2^(S*SCALE2).
// Barrier-free per-wave walk, 2048 blocks, 4 blocks/CU.
// ---------------------------------------------------------------------------
__global__ __launch_bounds__(256, 4) void attn_stats(
    const unsigned short* __restrict__ qkv, float* __restrict__ lpart) {
  __shared__ unsigned short qt[4][2][32 * 64];  // per-wave double buffer
  __shared__ float redL[4][2][64];
  const int tid = threadIdx.x, lane = tid & 63, w = tid >> 6;
  const int f = xcd_swz(blockIdx.y * 32 + blockIdx.x, 2048);
  const int half = f & 1, px = (f >> 1) & 15, bh = f >> 5;
  const int b = bh >> 4, h = bh & 15;
  const int sxA = px, sxB = 31 - px;
  const int sA = sxA * 64, sB = sxB * 64;
  const int m = half * 4 + w;  // t-tile stripe (mod 8)

  short8 kfA[4][2], kfB[4][2];
#pragma unroll
  for (int fn = 0; fn < 4; ++fn)
#pragma unroll
    for (int ks = 0; ks < 2; ++ks) {
      int d = 1024 + h * 64 + ks * 32 + ((lane >> 4) << 3);
      kfA[fn][ks] = *(const short8*)&qkv[(size_t)(b * T_SEQ + sA + fn * 16 +
                                                  (lane & 15)) * 3072 + d];
      kfB[fn][ks] = *(const short8*)&qkv[(size_t)(b * T_SEQ + sB + fn * 16 +
                                                  (lane & 15)) * 3072 + d];
    }
  float lA[4] = {0.f, 0.f, 0.f, 0.f}, lB[4] = {0.f, 0.f, 0.f, 0.f};

  auto stageQ = [&](int buf, int idx) {
    int t0 = idx * 32;
#pragma unroll
    for (int it = 0; it < 4; ++it) {
      int g = it * 64 + lane;
      int row = g >> 3;
      int col = (g & 7) ^ (row & 7);  // inverse-swizzled source
      g2lds16(qkv + ((size_t)(b * T_SEQ + t0 + row) * 3072 + h * 64 + col * 8),
              &qt[w][buf][it * 512]);
    }
  };

  auto accum = [&](const short8 (&af)[2], const short8 (&kf)[4][2],
                   float (&lacc)[4], int sBase, int tRow, bool diag) {
    f32x4 sc[4];
#pragma unroll
    for (int fn = 0; fn < 4; ++fn)
#pragma unroll
      for (int e = 0; e < 4; ++e) sc[fn][e] = 0.f;
    __builtin_amdgcn_s_setprio(1);
#pragma unroll
    for (int fn = 0; fn < 4; ++fn)
#pragma unroll
      for (int ks = 0; ks < 2; ++ks)
        sc[fn] = __builtin_amdgcn_mfma_f32_16x16x32_bf16(af[ks], kf[fn][ks],
                                                         sc[fn], 0, 0, 0);
    __builtin_amdgcn_s_setprio(0);
    if (diag) {
#pragma unroll
      for (int fn = 0; fn < 4; ++fn) {
        int s = sBase + fn * 16 + (lane & 15);
        float e0 = (tRow + 0 >= s) ? exp2f(sc[fn][0] * SCALE2) : 0.f;
        float e1 = (tRow + 1 >= s) ? exp2f(sc[fn][1] * SCALE2) : 0.f;
        float e2 = (tRow + 2 >= s) ? exp2f(sc[fn][2] * SCALE2) : 0.f;
        float e3 = (tRow + 3 >= s) ? exp2f(sc[fn][3] * SCALE2) : 0.f;
        lacc[fn] += (e0 + e1) + (e2 + e3);
      }
    } else {
#pragma unroll
      for (int fn = 0; fn < 4; ++fn) {
        float e0 = exp2f(sc[fn][0] * SCALE2);
        float e1 = exp2f(sc[fn][1] * SCALE2);
        float e2 = exp2f(sc[fn][2] * SCALE2);
        float e3 = exp2f(sc[fn][3] * SCALE2);
        lacc[fn] += (e0 + e1) + (e2 + e3);  // tree add: shorter dep chain
      }
    }
  };

  // first 32-row tile index >= 2*sxA in my stripe (idx == m mod 8)
  const int d0 = 2 * sxA - m;
  const int fi = m + (d0 > 0 ? (((d0 + 7) >> 3) << 3) : 0);
  int cur = 0;
  if (fi < 64) stageQ(0, fi);
  for (int idx = fi; idx < 64; idx += 8, cur ^= 1) {
    if (idx + 8 < 64) {
      stageQ(cur ^ 1, idx + 8);
      asm volatile("s_waitcnt vmcnt(4)" ::: "memory");  // cur buf resident
    } else {
      asm volatile("s_waitcnt vmcnt(0)" ::: "memory");
    }
    const int t0g = idx * 32;
    const bool doB = idx >= 2 * sxB;
#pragma unroll
    for (int mf = 0; mf < 2; ++mf) {
      short8 af[2];
#pragma unroll
      for (int ks = 0; ks < 2; ++ks) {
        int r = mf * 16 + (lane & 15);
        int c = (ks * 4 + (lane >> 4)) ^ (r & 7);
        af[ks] = *(const short8*)&qt[w][cur][r * 64 + c * 8];
      }
      int tRow = t0g + mf * 16 + ((lane >> 4) << 2);
      accum(af, kfA, lA, sA, tRow, idx <= 2 * sxA + 1);
      if (doB) accum(af, kfB, lB, sB, tRow, idx <= 2 * sxB + 1);
    }
  }
  // combine hi-groups (same col lives in lanes l, l+16, l+32, l+48)
#pragma unroll
  for (int fn = 0; fn < 4; ++fn) {
    lA[fn] += __shfl_down(lA[fn], 32);
    lA[fn] += __shfl_down(lA[fn], 16);
    lB[fn] += __shfl_down(lB[fn], 32);
    lB[fn] += __shfl_down(lB[fn], 16);
  }
  if (lane < 16) {
#pragma unroll
    for (int fn = 0; fn < 4; ++fn) {
      redL[w][0][fn * 16 + lane] = lA[fn];
      redL[w][1][fn * 16 + lane] = lB[fn];
    }
  }
  __syncthreads();
  if (tid < 128) {
    int which = tid >> 6;  // 0 -> A, 1 -> B
    float l = redL[0][which][lane] + redL[1][which][lane] +
              redL[2][which][lane] + redL[3][which][lane];
    int sbase = (which == 0) ? sA : sB;
    lpart[((size_t)half * 64 + bh) * T_SEQ + sbase + lane] = l;
  }
}

// ---------------------------------------------------------------------------
// Attention pass B (R16): row-tile pair per block, SPLIT plA/plB (16KB each,
// 64KB LDS total).  Phases: qkA -> bar -> {qkB || pvA} -> bar -> pvB -> bar.
// The merged phase mixes qkB's exp2/pack (VALU/trans) with pvA's MFMA in one
// stream -> dual-pipe overlap; one fewer barrier per A-tile.
// ---------------------------------------------------------------------------
__global__ __launch_bounds__(256, 2) void attn_pv(
    const unsigned short* __restrict__ qkv, const unsigned short* __restrict__ vT,
    unsigned short* __restrict__ o) {
  __shared__ unsigned short kbuf[2][64 * 64];
  __shared__ unsigned short vbuf[2][64 * 64];
  __shared__ unsigned short plA[128 * 64];
  __shared__ unsigned short plB[128 * 64];
  const int tid = threadIdx.x, lane = tid & 63, wid = tid >> 6;
  const int f = xcd_swz(blockIdx.y * 8 + blockIdx.x, 512);
  const int bx = f & 7, bh = f >> 3;
  const int b = bh >> 4, h = bh & 15;
  const int tA = bx * 128, tB = (15 - bx) * 128;
  const int nSTA = 2 * bx + 2, nSTB = 32 - 2 * bx;  // nSTA < nSTB always

  short8 qfA[2][2], qfB[2][2];
#pragma unroll
  for (int mf = 0; mf < 2; ++mf)
#pragma unroll
    for (int ks = 0; ks < 2; ++ks) {
      int d = h * 64 + ks * 32 + ((lane >> 4) << 3);
      int rloc = wid * 32 + mf * 16 + (lane & 15);
      qfA[mf][ks] =
          *(const short8*)&qkv[(size_t)(b * T_SEQ + tA + rloc) * 3072 + d];
      qfB[mf][ks] =
          *(const short8*)&qkv[(size_t)(b * T_SEQ + tB + rloc) * 3072 + d];
    }
  f32x4 oaccA[2][4], oaccB[2][4];
#pragma unroll
  for (int i = 0; i < 2; ++i)
#pragma unroll
    for (int j = 0; j < 4; ++j)
#pragma unroll
      for (int e = 0; e < 4; ++e) { oaccA[i][j][e] = 0.f; oaccB[i][j][e] = 0.f; }

  auto stage = [&](int buf, int st) {
#pragma unroll
    for (int it = 0; it < 2; ++it) {
      int g = it * 256 + tid;            // granule 0..511 (16B each)
      int row = g >> 3, colL = g & 7;
      int col = colL ^ (row & 7);        // inverse-swizzled source
      g2lds16(qkv + ((size_t)(b * T_SEQ + st * 64 + row) * 3072 + 1024 +
                     h * 64 + col * 8),
              &kbuf[buf][(it * 256 + wid * 64) * 8]);
      g2lds16(vT + ((size_t)(bh * 64 + row) * T_SEQ + st * 64 + col * 8),
              &vbuf[buf][(it * 256 + wid * 64) * 8]);
    }
  };

  // QK^T as mfma(K, Q): sc[fn][mf] has row = s-local, col = t-local.
  // Each lane holds P[t = wid*32+mf*16+(lane&15)][s = fn*16+(lane>>4)*4 + r]
  // -> 4 consecutive s = 8 contiguous bytes in row-major pl -> b64 store.
  auto qkstore = [&](const short8 (&qf)[2][2], unsigned short* pl, int tBase,
                     int s0, bool maskNeeded, int cur) {
    f32x4 sc[4][2];
#pragma unroll
    for (int i = 0; i < 4; ++i)
#pragma unroll
      for (int j = 0; j < 2; ++j)
#pragma unroll
        for (int e = 0; e < 4; ++e) sc[i][j][e] = 0.f;
    __builtin_amdgcn_s_setprio(1);
#pragma unroll
    for (int fn = 0; fn < 4; ++fn)
#pragma unroll
      for (int ks = 0; ks < 2; ++ks) {
        int r = fn * 16 + (lane & 15);
        int c = (ks * 4 + (lane >> 4)) ^ (r & 7);
        short8 kfr = *(const short8*)&kbuf[cur][r * 64 + c * 8];
        sc[fn][0] = __builtin_amdgcn_mfma_f32_16x16x32_bf16(kfr, qf[0][ks],
                                                            sc[fn][0], 0, 0, 0);
        sc[fn][1] = __builtin_amdgcn_mfma_f32_16x16x32_bf16(kfr, qf[1][ks],
                                                            sc[fn][1], 0, 0, 0);
      }
    __builtin_amdgcn_s_setprio(0);
#pragma unroll
    for (int mf = 0; mf < 2; ++mf) {
      int tl = wid * 32 + mf * 16 + (lane & 15);  // pl row
      int tG = tBase + tl;                         // global t
#pragma unroll
      for (int fn = 0; fn < 4; ++fn) {
        int sl = fn * 16 + ((lane >> 4) << 2);     // first of 4 consecutive s
        float p0 = exp2f(sc[fn][mf][0] * SCALE2);
        float p1 = exp2f(sc[fn][mf][1] * SCALE2);
        float p2 = exp2f(sc[fn][mf][2] * SCALE2);
        float p3 = exp2f(sc[fn][mf][3] * SCALE2);
        if (maskNeeded) {
          int sG = s0 + sl;
          p0 = (tG >= sG + 0) ? p0 : 0.f;
          p1 = (tG >= sG + 1) ? p1 : 0.f;
          p2 = (tG >= sG + 2) ? p2 : 0.f;
          p3 = (tG >= sG + 3) ? p3 : 0.f;
        }
        uint2 pk;
        pk.x = (unsigned)f2bf(p0) | ((unsigned)f2bf(p1) << 16);
        pk.y = (unsigned)f2bf(p2) | ((unsigned)f2bf(p3) << 16);
        int byteoff = tl * 128 + ((sl * 2) ^ ((tl & 7) << 4));
        *(uint2*)((char*)pl + byteoff) = pk;  // ds_write_b64
      }
    }
  };

  // PV: A = P (pl, swizzled), B^T = V-tile rows (vbuf, swizzled)
  auto pvphase = [&](f32x4 (&oacc)[2][4], const unsigned short* pl, int cur) {
    __builtin_amdgcn_s_setprio(1);
#pragma unroll
    for (int ks = 0; ks < 2; ++ks) {
      short8 pa[2];
#pragma unroll
      for (int mf = 0; mf < 2; ++mf) {
        int rowa = wid * 32 + mf * 16 + (lane & 15);
        int kb = ks * 64 + ((lane >> 4) << 4);
        pa[mf] = *(const short8*)((const char*)pl + rowa * 128 +
                                  (kb ^ ((rowa & 7) << 4)));
      }
#pragma unroll
      for (int df = 0; df < 4; ++df) {
        int r = df * 16 + (lane & 15);
        int c = (ks * 4 + (lane >> 4)) ^ (r & 7);
        short8 vb = *(const short8*)&vbuf[cur][r * 64 + c * 8];
        oacc[0][df] = __builtin_amdgcn_mfma_f32_16x16x32_bf16(pa[0], vb,
                                                              oacc[0][df], 0, 0, 0);
        oacc[1][df] = __builtin_amdgcn_mfma_f32_16x16x32_bf16(pa[1], vb,
                                                              oacc[1][df], 0, 0, 0);
      }
    }
    __builtin_amdgcn_s_setprio(0);
  };

  // lgkm-only handoff barrier (does NOT drain the vmcnt prefetch)
  auto bar_lgkm = [&]() {
    asm volatile("s_waitcnt lgkmcnt(0)" ::: "memory");
    __builtin_amdgcn_sched_barrier(0);
    __builtin_amdgcn_s_barrier();
    __builtin_amdgcn_sched_barrier(0);
  };

  stage(0, 0);
  asm volatile("s_waitcnt vmcnt(0)" ::: "memory");
  __builtin_amdgcn_sched_barrier(0);
  __builtin_amdgcn_s_barrier();  // tile 0 resident
  __builtin_amdgcn_sched_barrier(0);

  int cur = 0;
  for (int st = 0; st < nSTB; ++st) {
    const int s0 = st * 64;
    const bool doA = st < nSTA;  // block-uniform

    if (st + 1 < nSTB) stage(cur ^ 1, st + 1);  // in flight across all phases

    if (doA) {
      qkstore(qfA, plA, tA, s0, st >= nSTA - 2, cur);
      bar_lgkm();                 // plA visible
      // merged phase: qkB (exp2/VALU-heavy) || pvA (MFMA-heavy) -- disjoint
      // buffers (plB write, plA read), one instruction stream, dual pipes.
      qkstore(qfB, plB, tB, s0, st >= nSTB - 2, cur);
      pvphase(oaccA, plA, cur);
      bar_lgkm();                 // plB visible; plA reads retired
    } else {
      qkstore(qfB, plB, tB, s0, st >= nSTB - 2, cur);
      bar_lgkm();                 // plB visible
    }
    pvphase(oaccB, plB, cur);
    // end of tile: drain prefetch + all LDS ops, then release buffers
    asm volatile("s_waitcnt vmcnt(0) lgkmcnt(0)" ::: "memory");
    __builtin_amdgcn_sched_barrier(0);
    __builtin_amdgcn_s_barrier();
    __builtin_amdgcn_sched_barrier(0);
    cur ^= 1;
  }
  // write O as bf16 [B,T,C] (c = h*64+d)
#pragma unroll
  for (int mf = 0; mf < 2; ++mf)
#pragma unroll
    for (int df = 0; df < 4; ++df) {
      int d = h * 64 + df * 16 + (lane & 15);
      int ra = tA + wid * 32 + mf * 16 + ((lane >> 4) << 2);
      int rb = tB + wid * 32 + mf * 16 + ((lane >> 4) << 2);
#pragma unroll
      for (int r = 0; r < 4; ++r) {
        o[(size_t)(b * T_SEQ + ra + r) * 1024 + d] = f2bf(oaccA[mf][df][r]);
        o[(size_t)(b * T_SEQ + rb + r) * 1024 + d] = f2bf(oaccB[mf][df][r]);
      }
    }
}

// ---------------------------------------------------------------------------
extern "C" void kernel_launch(void* const* d_in, const int* in_sizes, int n_in,
                              void* d_out, int out_size, void* d_ws,
                              size_t ws_size, hipStream_t stream) {
  const float* x = (const float*)d_in[0];
  const float* Wq = (const float*)d_in[1];
  const float* Wk = (const float*)d_in[2];
  const float* Wv = (const float*)d_in[3];
  const float* Wo = (const float*)d_in[4];
  const float* bo = (const float*)d_in[5];
  const float* g1 = (const float*)d_in[6];
  const float* b1 = (const float*)d_in[7];
  const float* g2 = (const float*)d_in[8];
  const float* b2 = (const float*)d_in[9];
  const float* W1 = (const float*)d_in[10];
  const float* bf1 = (const float*)d_in[11];
  const float* W2 = (const float*)d_in[12];
  const float* bf2 = (const float*)d_in[13];
  float* out = (float*)d_out;

  char* ws = (char*)d_ws;
  size_t off = 0;
  auto alloc = [&](size_t bytes) {
    char* p = ws + off;
    off += (bytes + 255) & ~(size_t)255;
    return p;
  };
  unsigned short* Wqkv = (unsigned short*)alloc(3072ull * 1024 * 2);
  unsigned short* WoT = (unsigned short*)alloc(1024ull * 1024 * 2);
  unsigned short* W1T = (unsigned short*)alloc(4096ull * 1024 * 2);
  unsigned short* W2T = (unsigned short*)alloc(1024ull * 4096 * 2);
  unsigned short* hbuf = (unsigned short*)alloc(8192ull * 1024 * 2);  // h, then o
  char* regionE = alloc(8192ull * 3072 * 2 + 64ull * 64 * 2048 * 2);
  unsigned short* qkv = (unsigned short*)regionE;           // live: QKV..attn
  unsigned short* vT = (unsigned short*)(regionE + 8192ull * 3072 * 2);
  unsigned short* act = (unsigned short*)regionE;           // live: FFN
  float* lbuf = (float*)alloc(128ull * 2048 * 4);           // 2 halves of partials
  float* x1 = (float*)alloc(8192ull * 1024 * 4);
  unsigned short* fbuf = (unsigned short*)alloc(8192ull * 1024 * 2);
  unsigned short* obuf = hbuf;  // h dead after QKV GEMM

  (void)in_sizes; (void)n_in; (void)out_size; (void)ws_size;

  const size_t LDS128 = (2 * 16384 + 2 * 128 * 64) * 2;  // 96 KB
  const size_t LDS256 = (2 * 16384 + 2 * 256 * 64) * 2;  // 128 KB

  // weight packing (B^T bf16 layouts)
  pack_qkv<<<dim3(16, 16, 3), 256, 0, stream>>>(Wq, Wk, Wv, Wqkv);
  transpose_cast<<<dim3(16, 16), 256, 0, stream>>>(Wo, WoT, 1024, 1024);
  transpose_cast<<<dim3(16, 64), 256, 0, stream>>>(W1, W1T, 1024, 4096);
  transpose_cast<<<dim3(64, 16), 256, 0, stream>>>(W2, W2T, 4096, 1024);
  // LN1 -> h
  ln_bf16<<<8192, 256, 0, stream>>>(x, g1, b1, hbuf);
  // QKV projection: [8192,1024]@[1024,3072]  (768 blocks = 3 exact waves)
  gemm256<0, 128><<<dim3(24, 32), 512, LDS128, stream>>>(
      hbuf, Wqkv, 8192, 3072, 1024, qkv, nullptr, nullptr, nullptr);
  // attention stats partials (2048 blocks, barrier-free waves)
  attn_stats<<<dim3(32, 64), 256, 0, stream>>>(qkv, lbuf);
  // V transpose, pre-scaled by combined linv
  vtrans<<<dim3(32, 64), 256, 0, stream>>>(qkv, lbuf, vT);
  // attention PV
  attn_pv<<<dim3(8, 64), 256, 0, stream>>>(qkv, vT, obuf);
  // x1 = x + O@Wo + bo   (256 blocks = 1 exact wave)
  gemm256<1, 128><<<dim3(8, 32), 512, LDS128, stream>>>(
      obuf, WoT, 8192, 1024, 1024, nullptr, x1, bo, x);
  // LN2 -> f
  ln_bf16<<<8192, 256, 0, stream>>>(x1, g2, b2, fbuf);
  // FFN1: relu(f@W1 + bf1) -> act bf16 [8192,4096]  (512 blocks = 2 waves)
  gemm256<2, 256><<<dim3(16, 32), 512, LDS256, stream>>>(
      fbuf, W1T, 8192, 4096, 1024, act, nullptr, bf1, nullptr);
  // FFN2 + residual: out = x1 + act@W2 + bf2   (256 blocks = 1 exact wave)
  gemm256<1, 128><<<dim3(8, 32), 512, LDS128, stream>>>(
      act, W2T, 8192, 1024, 4096, nullptr, out, bf2, x1);
}